// Round 6
// baseline (547.269 us; speedup 1.0000x reference)
//
#include <hip/hip_runtime.h>
#include <hip/hip_cooperative_groups.h>
#include <math.h>

namespace cg = cooperative_groups;

#define N 16384
#define GC 16            // grid cells per dim
#define NCELL (GC*GC*GC) // 4096

__device__ __forceinline__ float wsum(float v){
  #pragma unroll
  for(int m=32;m>0;m>>=1) v += __shfl_xor(v,m,64);
  return v;
}

// branchless lexicographic (d,idx) top-3 insert; matches jax top_k stable tie-break
__device__ __forceinline__ void lexins(float dd,int j2,
    float&D0,float&D1,float&D2,int&I0,int&I1,int&I2){
  bool lt0=(dd<D0)||((dd==D0)&&(j2<I0));
  bool lt1=(dd<D1)||((dd==D1)&&(j2<I1));
  bool lt2=(dd<D2)||((dd==D2)&&(j2<I2));
  float nD2=lt1?D1:(lt2?dd:D2); int nI2=lt1?I1:(lt2?j2:I2);
  float nD1=lt0?D0:(lt1?dd:D1); int nI1=lt0?I0:(lt1?j2:I1);
  float nD0=lt0?dd:D0;          int nI0=lt0?j2:I0;
  D0=nD0;D1=nD1;D2=nD2;I0=nI0;I1=nI1;I2=nI2;
}

// reference-exact squared distance: dd = rn(rn(qs+cs) - 2*dot), dot FMA chain
__device__ __forceinline__ float refdist(float qx,float qy,float qz,float qs,float4 cv){
  float dot=__fmaf_rn(qz,cv.z,__fmaf_rn(qy,cv.y,__fmul_rn(qx,cv.x)));
  float sc =__fadd_rn(qs,cv.w);
  return __fmaf_rn(-2.0f,dot,sc);
}

// One cooperative kernel: 256 blocks x 256 threads (65536 = N*4 threads).
// Phases separated by grid.sync(); all numerics identical to the passing
// round-5 multi-kernel version.
__global__ __launch_bounds__(256) void fused(
    const float* __restrict__ in,
    const float* __restrict__ g1, const float* __restrict__ b1,
    const float* __restrict__ g2, const float* __restrict__ b2,
    const float* __restrict__ coords,
    const float* __restrict__ gg, const float* __restrict__ gb,
    const float* __restrict__ W1, const float* __restrict__ bb1,
    const float* __restrict__ W2, const float* __restrict__ bb2,
    float* __restrict__ out,
    float* __restrict__ x, float* __restrict__ xn,
    float4* __restrict__ c4, float4* __restrict__ sc4, int* __restrict__ sidx,
    int* __restrict__ cellCnt, int* __restrict__ cellSt, int* __restrict__ cellCur,
    int* __restrict__ knn, float* __restrict__ ew, float* __restrict__ dis,
    float* __restrict__ h, float* __restrict__ a1){
  cg::grid_group grid = cg::this_grid();
  __shared__ float Ws[4096];
  __shared__ int scanbuf[256];
  int tid=threadIdx.x, bid=blockIdx.x;
  int gt=bid*256+tid;
  int wave=tid>>6, lane=tid&63;
  int gwave=bid*4+wave;            // 0..1023; each handles 16 nodes

  // ---- P0: zero cell histogram ----
  if(gt<NCELL) cellCnt[gt]=0;
  grid.sync();

  // ---- P1: LN -> x2 -> LN, row norms, c4=(x,y,z,sq), cell histogram ----
  for(int r=0;r<16;r++){
    int row=gwave*16+r;
    float v=in[row*64+lane];
    float m=wsum(v)*(1.0f/64.0f);
    float d=v-m;
    float var=wsum(d*d)*(1.0f/64.0f);
    float y=d*(1.0f/sqrtf(var+1e-5f))*g1[lane]+b1[lane];
    y=y+y;  // transformer stubbed as identity + shortcut
    float m2=wsum(y)*(1.0f/64.0f);
    float d2=y-m2;
    float var2=wsum(d2*d2)*(1.0f/64.0f);
    float z=d2*(1.0f/sqrtf(var2+1e-5f))*g2[lane]+b2[lane];
    x[row*64+lane]=z;
    float s=wsum(z*z);
    if(lane==0){
      xn[row]=fmaxf(sqrtf(s),1e-8f);
      float a=coords[row*3+0],b=coords[row*3+1],c=coords[row*3+2];
      float sq=__fadd_rn(__fadd_rn(__fmul_rn(a,a),__fmul_rn(b,b)),__fmul_rn(c,c));
      c4[row]=make_float4(a,b,c,sq);
      int cx=min(GC-1,(int)(a*(float)GC)), cy=min(GC-1,(int)(b*(float)GC)),
          cz=min(GC-1,(int)(c*(float)GC));
      atomicAdd(&cellCnt[(cz*GC+cy)*GC+cx],1);
    }
  }
  grid.sync();

  // ---- P2: exclusive prefix sum over 4096 cell counts (block 0 only) ----
  if(bid==0){
    int base=tid*16, s=0, loc[16];
    #pragma unroll
    for(int k=0;k<16;k++){ loc[k]=s; s+=cellCnt[base+k]; }
    scanbuf[tid]=s; __syncthreads();
    for(int off=1;off<256;off<<=1){
      int t=(tid>=off)?scanbuf[tid-off]:0;
      __syncthreads();
      scanbuf[tid]+=t;
      __syncthreads();
    }
    int excl=scanbuf[tid]-s;
    #pragma unroll
    for(int k=0;k<16;k++){ cellSt[base+k]=excl+loc[k]; cellCur[base+k]=excl+loc[k]; }
    if(tid==255) cellSt[NCELL]=scanbuf[255];
  }
  grid.sync();

  // ---- P3: scatter points into cell-sorted order ----
  if(gt<N){
    float4 v=c4[gt];
    int cx=min(GC-1,(int)(v.x*(float)GC)), cy=min(GC-1,(int)(v.y*(float)GC)),
        cz=min(GC-1,(int)(v.z*(float)GC));
    int pos=atomicAdd(&cellCur[(cz*GC+cy)*GC+cx],1);
    sc4[pos]=v; sidx[pos]=gt;
  }
  grid.sync();

  // ---- P4: grid KNN (4 lanes/query) + in-wave brute-force fallback ----
  {
    int slot=gt>>2, part=gt&3;
    float4 qv=sc4[slot]; int q=sidx[slot];
    float qx=qv.x,qy=qv.y,qz=qv.z,qs=qv.w;
    int cx=min(GC-1,(int)(qx*(float)GC)), cy=min(GC-1,(int)(qy*(float)GC)),
        cz=min(GC-1,(int)(qz*(float)GC));
    float D0=1e30f,D1=1e30f,D2=1e30f; int I0=0x7fffffff,I1=0x7fffffff,I2=0x7fffffff;
    int xlo=max(cx-1,0), xhi=min(cx+1,GC-1);
    for(int r=part;r<9;r+=4){
      int z2=cz+r/3-1, y2=cy+r%3-1;
      if(z2<0||z2>=GC||y2<0||y2>=GC) continue;
      int rowb=(z2*GC+y2)*GC;
      int p0=cellSt[rowb+xlo], p1=cellSt[rowb+xhi+1];  // x-cells contiguous
      for(int p=p0;p<p1;p++){
        float4 cv=sc4[p]; int j2=sidx[p];
        float dd=refdist(qx,qy,qz,qs,cv);
        dd=(j2==q)?1e30f:dd;
        lexins(dd,j2,D0,D1,D2,I0,I1,I2);
      }
    }
    #pragma unroll
    for(int m=1;m<4;m<<=1){
      float e0=__shfl_xor(D0,m),e1=__shfl_xor(D1,m),e2=__shfl_xor(D2,m);
      int   f0=__shfl_xor(I0,m),f1=__shfl_xor(I1,m),f2=__shfl_xor(I2,m);
      lexins(e0,f0,D0,D1,D2,I0,I1,I2);
      lexins(e1,f1,D0,D1,D2,I0,I1,I2);
      lexins(e2,f2,D0,D1,D2,I0,I1,I2);
    }
    bool flg=false;
    if(part==0){
      const float cw=1.0f/(float)GC;
      float mg=1e30f;
      mg=fminf(mg,(cx>0)?(qx-(float)(cx-1)*cw):1e30f);
      mg=fminf(mg,(cx<GC-1)?((float)(cx+2)*cw-qx):1e30f);
      mg=fminf(mg,(cy>0)?(qy-(float)(cy-1)*cw):1e30f);
      mg=fminf(mg,(cy<GC-1)?((float)(cy+2)*cw-qy):1e30f);
      mg=fminf(mg,(cz>0)?(qz-(float)(cz-1)*cw):1e30f);
      mg=fminf(mg,(cz<GC-1)?((float)(cz+2)*cw-qz):1e30f);
      float mg2=mg*mg*(1.0f-1e-5f);   // slack for dd rounding
      flg=!(D2<mg2);
      if(!flg){ knn[q*3+0]=I0; knn[q*3+1]=I1; knn[q*3+2]=I2; }
    }
    // rare fallback (~1e-5 of queries): whole wave brute-forces flagged queries
    unsigned long long mask=__ballot(flg);
    while(mask){
      int b=__ffsll((unsigned long long)mask)-1; mask&=mask-1;
      int qb=__shfl(q,b);
      float bx=__shfl(qx,b),by=__shfl(qy,b),bz=__shfl(qz,b),bs=__shfl(qs,b);
      float E0=1e30f,E1=1e30f,E2=1e30f; int F0=0x7fffffff,F1=0x7fffffff,F2=0x7fffffff;
      for(int j=lane;j<N;j+=64){
        float4 cv=c4[j];
        float dd=refdist(bx,by,bz,bs,cv);
        dd=(j==qb)?1e30f:dd;
        lexins(dd,j,E0,E1,E2,F0,F1,F2);
      }
      #pragma unroll
      for(int m=1;m<64;m<<=1){
        float e0=__shfl_xor(E0,m),e1=__shfl_xor(E1,m),e2=__shfl_xor(E2,m);
        int   f0=__shfl_xor(F0,m),f1=__shfl_xor(F1,m),f2=__shfl_xor(F2,m);
        lexins(e0,f0,E0,E1,E2,F0,F1,F2);
        lexins(e1,f1,E0,E1,E2,F0,F1,F2);
        lexins(e2,f2,E0,E1,E2,F0,F1,F2);
      }
      if(lane==0){ knn[qb*3+0]=F0; knn[qb*3+1]=F1; knn[qb*3+2]=F2; }
    }
  }
  grid.sync();

  // ---- P5: edge weights + dis (16 nodes/wave), then gemm1 h = x@W1 ----
  for(int k=tid;k<4096;k+=256) Ws[k]=W1[k];   // stage W1 while ew runs
  for(int r=0;r<16;r++){
    int i=gwave*16+r;
    float xi=x[i*64+lane];
    float ni=xn[i];
    float ssum=0.f;
    #pragma unroll
    for(int m=0;m<3;m++){
      int s=knn[i*3+m];
      float xs=x[s*64+lane];
      float dot=wsum(xs*xi);
      float cv=dot/(xn[s]*ni);
      float e=1.f/(1.f+expf(-cv));
      if(lane==0) ew[i*3+m]=e;
      ssum+=e;
    }
    if(lane==0) dis[i]=1.f/sqrtf(ssum+1.0f);  // deg = 1 (self loop) + sum(ew)
  }
  __syncthreads();
  {
    const float4* X4=(const float4*)x;
    for(int rg=0;rg<4;rg++){
      int r0=gwave*16+rg*4;
      float acc[4]={0.f,0.f,0.f,0.f};
      #pragma unroll
      for(int k4=0;k4<16;k4++){
        float w0=Ws[(k4*4+0)*64+lane];
        float w1=Ws[(k4*4+1)*64+lane];
        float w2=Ws[(k4*4+2)*64+lane];
        float w3=Ws[(k4*4+3)*64+lane];
        #pragma unroll
        for(int rr=0;rr<4;rr++){
          float4 xv=X4[(r0+rr)*16+k4];
          acc[rr]=fmaf(xv.x,w0,acc[rr]);
          acc[rr]=fmaf(xv.y,w1,acc[rr]);
          acc[rr]=fmaf(xv.z,w2,acc[rr]);
          acc[rr]=fmaf(xv.w,w3,acc[rr]);
        }
      }
      #pragma unroll
      for(int rr=0;rr<4;rr++) h[(r0+rr)*64+lane]=acc[rr];
    }
  }
  grid.sync();

  // ---- P6: GCN aggregate 1 + bias + LN + ReLU -> a1 ----
  for(int r=0;r<16;r++){
    int i=gwave*16+r;
    float di=dis[i];
    float acc=h[i*64+lane]*(di*di);           // self loop, ew=1
    #pragma unroll
    for(int m=0;m<3;m++){
      int s=knn[i*3+m];
      acc+=h[s*64+lane]*(dis[s]*ew[i*3+m]*di);
    }
    acc+=bb1[lane];
    float mu=wsum(acc)*(1.0f/64.0f);
    float dd=acc-mu;
    float var=wsum(dd*dd)*(1.0f/64.0f);
    float y=dd*(1.0f/sqrtf(var+1e-5f))*gg[lane]+gb[lane];
    a1[i*64+lane]=fmaxf(y,0.0f);
  }
  grid.sync();

  // ---- P7: gemm2 h = a1@W2 ----
  for(int k=tid;k<4096;k+=256) Ws[k]=W2[k];
  __syncthreads();
  {
    const float4* A4=(const float4*)a1;
    for(int rg=0;rg<4;rg++){
      int r0=gwave*16+rg*4;
      float acc[4]={0.f,0.f,0.f,0.f};
      #pragma unroll
      for(int k4=0;k4<16;k4++){
        float w0=Ws[(k4*4+0)*64+lane];
        float w1=Ws[(k4*4+1)*64+lane];
        float w2=Ws[(k4*4+2)*64+lane];
        float w3=Ws[(k4*4+3)*64+lane];
        #pragma unroll
        for(int rr=0;rr<4;rr++){
          float4 xv=A4[(r0+rr)*16+k4];
          acc[rr]=fmaf(xv.x,w0,acc[rr]);
          acc[rr]=fmaf(xv.y,w1,acc[rr]);
          acc[rr]=fmaf(xv.z,w2,acc[rr]);
          acc[rr]=fmaf(xv.w,w3,acc[rr]);
        }
      }
      #pragma unroll
      for(int rr=0;rr<4;rr++) h[(r0+rr)*64+lane]=acc[rr];
    }
  }
  grid.sync();

  // ---- P8: GCN aggregate 2 + bias + residual: out = 2x + agg(h)+b2 ----
  for(int r=0;r<16;r++){
    int i=gwave*16+r;
    float di=dis[i];
    float acc=h[i*64+lane]*(di*di);
    #pragma unroll
    for(int m=0;m<3;m++){
      int s=knn[i*3+m];
      acc+=h[s*64+lane]*(dis[s]*ew[i*3+m]*di);
    }
    acc+=bb2[lane];
    float xv=x[i*64+lane];
    out[i*64+lane]=(acc+xv)+xv;  // (gcn2 + x) + shortcut, shortcut == x
  }
}

extern "C" void kernel_launch(void* const* d_in, const int* in_sizes, int n_in,
                              void* d_out, int out_size, void* d_ws, size_t ws_size,
                              hipStream_t stream){
  const float* feat  =(const float*)d_in[0];
  // d_in[1] edge_index_tran, d_in[2] edge_attr_rpe, d_in[3] norm_index: unused by reference
  const float* coords=(const float*)d_in[4];
  const float* g1 =(const float*)d_in[5];
  const float* b1n=(const float*)d_in[6];
  const float* g2 =(const float*)d_in[7];
  const float* b2n=(const float*)d_in[8];
  const float* gg =(const float*)d_in[9];
  const float* gb =(const float*)d_in[10];
  const float* W1 =(const float*)d_in[11];
  const float* bb1=(const float*)d_in[12];
  const float* W2 =(const float*)d_in[13];
  const float* bb2=(const float*)d_in[14];
  float* out=(float*)d_out;

  char* ws=(char*)d_ws;
  size_t o=0;
  float*  x      =(float*) (ws+o); o+=(size_t)N*64*4;    // post-LN2 features
  float*  h      =(float*) (ws+o); o+=(size_t)N*64*4;    // GEMM output (reused)
  float*  a1     =(float*) (ws+o); o+=(size_t)N*64*4;    // activated GCN1 output
  float*  xn     =(float*) (ws+o); o+=(size_t)N*4;       // row norms of x
  float*  ew     =(float*) (ws+o); o+=(size_t)N*3*4;     // knn edge weights
  float*  dis    =(float*) (ws+o); o+=(size_t)N*4;       // 1/sqrt(deg)
  int*    knn    =(int*)   (ws+o); o+=(size_t)N*3*4;     // neighbor indices
  float4* c4     =(float4*)(ws+o); o+=(size_t)N*16;      // (x,y,z,sq) original order
  float4* sc4    =(float4*)(ws+o); o+=(size_t)N*16;      // cell-sorted
  int*    sidx   =(int*)   (ws+o); o+=(size_t)N*4;       // sorted -> original
  int*    cellCnt=(int*)   (ws+o); o+=(size_t)NCELL*4;
  int*    cellSt =(int*)   (ws+o); o+=(size_t)(NCELL+1)*4;
  int*    cellCur=(int*)   (ws+o); o+=(size_t)NCELL*4;
  (void)ws_size; (void)in_sizes; (void)n_in; (void)out_size;

  void* args[]={
    (void*)&feat,(void*)&g1,(void*)&b1n,(void*)&g2,(void*)&b2n,
    (void*)&coords,(void*)&gg,(void*)&gb,
    (void*)&W1,(void*)&bb1,(void*)&W2,(void*)&bb2,
    (void*)&out,
    (void*)&x,(void*)&xn,(void*)&c4,(void*)&sc4,(void*)&sidx,
    (void*)&cellCnt,(void*)&cellSt,(void*)&cellCur,
    (void*)&knn,(void*)&ew,(void*)&dis,(void*)&h,(void*)&a1};
  hipLaunchCooperativeKernel((void*)fused, dim3(256), dim3(256), args, 0, stream);
}

// Round 7
// 318.181 us; speedup vs baseline: 1.7200x; 1.7200x over previous
//
#include <hip/hip_runtime.h>
#include <math.h>

#define N 16384
#define GC 16            // grid cells per dim
#define NCELL (GC*GC*GC) // 4096

__device__ __forceinline__ float wsum(float v){
  #pragma unroll
  for(int m=32;m>0;m>>=1) v += __shfl_xor(v,m,64);
  return v;
}

// branchless lexicographic (d,idx) top-3 insert; matches jax top_k stable tie-break
__device__ __forceinline__ void lexins(float dd,int j2,
    float&D0,float&D1,float&D2,int&I0,int&I1,int&I2){
  bool lt0=(dd<D0)||((dd==D0)&&(j2<I0));
  bool lt1=(dd<D1)||((dd==D1)&&(j2<I1));
  bool lt2=(dd<D2)||((dd==D2)&&(j2<I2));
  float nD2=lt1?D1:(lt2?dd:D2); int nI2=lt1?I1:(lt2?j2:I2);
  float nD1=lt0?D0:(lt1?dd:D1); int nI1=lt0?I0:(lt1?j2:I1);
  float nD0=lt0?dd:D0;          int nI0=lt0?j2:I0;
  D0=nD0;D1=nD1;D2=nD2;I0=nI0;I1=nI1;I2=nI2;
}

// reference-exact squared distance: dd = rn(rn(qs+cs) - 2*dot), dot FMA chain
__device__ __forceinline__ float refdist(float qx,float qy,float qz,float qs,float4 cv){
  float dot=__fmaf_rn(qz,cv.z,__fmaf_rn(qy,cv.y,__fmul_rn(qx,cv.x)));
  float sc =__fadd_rn(qs,cv.w);
  return __fmaf_rn(-2.0f,dot,sc);
}

// ---- K1: LN -> x2 -> LN, row L2 norms, c4=(x,y,z,sq). One wave per row. ----
__global__ __launch_bounds__(256) void ln_kernel(const float* __restrict__ in,
    const float* __restrict__ g1,const float* __restrict__ b1,
    const float* __restrict__ g2,const float* __restrict__ b2,
    const float* __restrict__ coords,
    float* __restrict__ x, float* __restrict__ xn, float4* __restrict__ c4){
  int wave=threadIdx.x>>6, lane=threadIdx.x&63;
  int row=blockIdx.x*4+wave;
  float v=in[row*64+lane];
  float m=wsum(v)*(1.0f/64.0f);
  float d=v-m;
  float var=wsum(d*d)*(1.0f/64.0f);
  float y=d*(1.0f/sqrtf(var+1e-5f))*g1[lane]+b1[lane];
  y=y+y;  // transformer stubbed as identity + shortcut
  float m2=wsum(y)*(1.0f/64.0f);
  float d2=y-m2;
  float var2=wsum(d2*d2)*(1.0f/64.0f);
  float z=d2*(1.0f/sqrtf(var2+1e-5f))*g2[lane]+b2[lane];
  x[row*64+lane]=z;
  float s=wsum(z*z);
  if(lane==0){
    xn[row]=fmaxf(sqrtf(s),1e-8f);
    float a=coords[row*3+0],b=coords[row*3+1],c=coords[row*3+2];
    float sq=__fadd_rn(__fadd_rn(__fmul_rn(a,a),__fmul_rn(b,b)),__fmul_rn(c,c));
    c4[row]=make_float4(a,b,c,sq);
  }
}

// ---- K2: single-block prep: LDS histogram + scan + scatter. ----
// Replaces memset + global hist + scan + scatter (4 ops -> 1 dispatch).
// Scatter order within a cell is nondeterministic; lexins tie-break is
// order-independent, so results are unaffected.
__global__ __launch_bounds__(256) void prep(const float4* __restrict__ c4,
    float4* __restrict__ sc4, int* __restrict__ sidx, int* __restrict__ cellSt){
  __shared__ int cnt[NCELL];
  __shared__ int scanbuf[256];
  int tid=threadIdx.x;
  for(int k=tid;k<NCELL;k+=256) cnt[k]=0;
  __syncthreads();
  for(int i=tid;i<N;i+=256){
    float4 v=c4[i];
    int cx=min(GC-1,(int)(v.x*(float)GC)), cy=min(GC-1,(int)(v.y*(float)GC)),
        cz=min(GC-1,(int)(v.z*(float)GC));
    atomicAdd(&cnt[(cz*GC+cy)*GC+cx],1);
  }
  __syncthreads();
  int base=tid*16, s=0, loc[16];
  #pragma unroll
  for(int k=0;k<16;k++){ loc[k]=s; s+=cnt[base+k]; }
  scanbuf[tid]=s; __syncthreads();
  for(int off=1;off<256;off<<=1){
    int t=(tid>=off)?scanbuf[tid-off]:0;
    __syncthreads();
    scanbuf[tid]+=t;
    __syncthreads();
  }
  int excl=scanbuf[tid]-s;
  #pragma unroll
  for(int k=0;k<16;k++){ cellSt[base+k]=excl+loc[k]; cnt[base+k]=excl+loc[k]; }
  if(tid==255) cellSt[NCELL]=excl+s;
  __syncthreads();
  for(int i=tid;i<N;i+=256){
    float4 v=c4[i];
    int cx=min(GC-1,(int)(v.x*(float)GC)), cy=min(GC-1,(int)(v.y*(float)GC)),
        cz=min(GC-1,(int)(v.z*(float)GC));
    int pos=atomicAdd(&cnt[(cz*GC+cy)*GC+cx],1);
    sc4[pos]=v; sidx[pos]=i;
  }
}

// ---- K3: grid KNN (4 lanes/query, in-wave fallback) + ew + gemm1. ----
// 256 blocks x 256 threads; each wave owns 16 sorted slots: KNN them,
// then edge-weights (knn broadcast via shuffles), then h = x@W1 rows.
__global__ __launch_bounds__(256) void knn_ew_gemm1(const float4* __restrict__ sc4,
    const int* __restrict__ sidx, const int* __restrict__ cellSt,
    const float4* __restrict__ c4, const float* __restrict__ x,
    const float* __restrict__ xn, const float* __restrict__ W1,
    int* __restrict__ knn, float* __restrict__ ew, float* __restrict__ dis,
    float* __restrict__ h){
  __shared__ float Ws[4096];
  int tid=threadIdx.x, bid=blockIdx.x;
  for(int k=tid;k<4096;k+=256) Ws[k]=W1[k];    // staged for gemm phase
  int gt=bid*256+tid;
  int lane=tid&63;
  int slot=gt>>2, part=gt&3;

  // --- KNN (numerics identical to r5/r6) ---
  float4 qv=sc4[slot]; int q=sidx[slot];
  float qx=qv.x,qy=qv.y,qz=qv.z,qs=qv.w;
  int cx=min(GC-1,(int)(qx*(float)GC)), cy=min(GC-1,(int)(qy*(float)GC)),
      cz=min(GC-1,(int)(qz*(float)GC));
  float D0=1e30f,D1=1e30f,D2=1e30f; int I0=0x7fffffff,I1=0x7fffffff,I2=0x7fffffff;
  int xlo=max(cx-1,0), xhi=min(cx+1,GC-1);
  for(int r=part;r<9;r+=4){
    int z2=cz+r/3-1, y2=cy+r%3-1;
    if(z2<0||z2>=GC||y2<0||y2>=GC) continue;
    int rowb=(z2*GC+y2)*GC;
    int p0=cellSt[rowb+xlo], p1=cellSt[rowb+xhi+1];  // x-cells contiguous
    for(int p=p0;p<p1;p++){
      float4 cv=sc4[p]; int j2=sidx[p];
      float dd=refdist(qx,qy,qz,qs,cv);
      dd=(j2==q)?1e30f:dd;
      lexins(dd,j2,D0,D1,D2,I0,I1,I2);
    }
  }
  #pragma unroll
  for(int m=1;m<4;m<<=1){
    float e0=__shfl_xor(D0,m),e1=__shfl_xor(D1,m),e2=__shfl_xor(D2,m);
    int   f0=__shfl_xor(I0,m),f1=__shfl_xor(I1,m),f2=__shfl_xor(I2,m);
    lexins(e0,f0,D0,D1,D2,I0,I1,I2);
    lexins(e1,f1,D0,D1,D2,I0,I1,I2);
    lexins(e2,f2,D0,D1,D2,I0,I1,I2);
  }
  bool flg=false;
  if(part==0){
    const float cw=1.0f/(float)GC;
    float mg=1e30f;
    mg=fminf(mg,(cx>0)?(qx-(float)(cx-1)*cw):1e30f);
    mg=fminf(mg,(cx<GC-1)?((float)(cx+2)*cw-qx):1e30f);
    mg=fminf(mg,(cy>0)?(qy-(float)(cy-1)*cw):1e30f);
    mg=fminf(mg,(cy<GC-1)?((float)(cy+2)*cw-qy):1e30f);
    mg=fminf(mg,(cz>0)?(qz-(float)(cz-1)*cw):1e30f);
    mg=fminf(mg,(cz<GC-1)?((float)(cz+2)*cw-qz):1e30f);
    float mg2=mg*mg*(1.0f-1e-5f);   // slack for dd rounding
    flg=!(D2<mg2);
  }
  // rare fallback (~1e-5 of queries): whole wave brute-forces flagged queries
  unsigned long long mask=__ballot(flg);
  while(mask){
    int b=__ffsll((unsigned long long)mask)-1; mask&=mask-1;
    int qb=__shfl(q,b);
    float bx=__shfl(qx,b),by=__shfl(qy,b),bz=__shfl(qz,b),bs=__shfl(qs,b);
    float E0=1e30f,E1=1e30f,E2=1e30f; int F0=0x7fffffff,F1=0x7fffffff,F2=0x7fffffff;
    for(int j=lane;j<N;j+=64){
      float4 cv=c4[j];
      float dd=refdist(bx,by,bz,bs,cv);
      dd=(j==qb)?1e30f:dd;
      lexins(dd,j,E0,E1,E2,F0,F1,F2);
    }
    #pragma unroll
    for(int m=1;m<64;m<<=1){
      float e0=__shfl_xor(E0,m),e1=__shfl_xor(E1,m),e2=__shfl_xor(E2,m);
      int   f0=__shfl_xor(F0,m),f1=__shfl_xor(F1,m),f2=__shfl_xor(F2,m);
      lexins(e0,f0,E0,E1,E2,F0,F1,F2);
      lexins(e1,f1,E0,E1,E2,F0,F1,F2);
      lexins(e2,f2,E0,E1,E2,F0,F1,F2);
    }
    if(lane==b){ I0=F0; I1=F1; I2=F2; }   // fix the owning lane's registers
  }
  if(part==0){ knn[q*3+0]=I0; knn[q*3+1]=I1; knn[q*3+2]=I2; }

  // --- ew + dis for the wave's 16 queries (results live in lanes 4r) ---
  int qrow[16];
  for(int r=0;r<16;r++){
    int qi=__shfl(q,4*r);
    int s0=__shfl(I0,4*r), s1=__shfl(I1,4*r), s2=__shfl(I2,4*r);
    qrow[r]=qi;
    float xi=x[qi*64+lane];
    float ni=xn[qi];
    float ssum=0.f;
    int ss[3]={s0,s1,s2};
    #pragma unroll
    for(int m=0;m<3;m++){
      int s=ss[m];
      float xs=x[s*64+lane];
      float dot=wsum(xs*xi);
      float cv=dot/(xn[s]*ni);
      float e=1.f/(1.f+expf(-cv));
      if(lane==0) ew[qi*3+m]=e;
      ssum+=e;
    }
    if(lane==0) dis[qi]=1.f/sqrtf(ssum+1.0f);  // deg = 1 (self loop) + sum(ew)
  }

  // --- gemm1: h[row] = x[row] @ W1 for the wave's 16 rows ---
  __syncthreads();                       // Ws ready
  const float4* X4=(const float4*)x;
  for(int rg=0;rg<4;rg++){
    float acc[4]={0.f,0.f,0.f,0.f};
    #pragma unroll
    for(int k4=0;k4<16;k4++){
      float w0=Ws[(k4*4+0)*64+lane];
      float w1=Ws[(k4*4+1)*64+lane];
      float w2=Ws[(k4*4+2)*64+lane];
      float w3=Ws[(k4*4+3)*64+lane];
      #pragma unroll
      for(int rr=0;rr<4;rr++){
        float4 xv=X4[qrow[rg*4+rr]*16+k4];
        acc[rr]=fmaf(xv.x,w0,acc[rr]);
        acc[rr]=fmaf(xv.y,w1,acc[rr]);
        acc[rr]=fmaf(xv.z,w2,acc[rr]);
        acc[rr]=fmaf(xv.w,w3,acc[rr]);
      }
    }
    #pragma unroll
    for(int rr=0;rr<4;rr++) h[qrow[rg*4+rr]*64+lane]=acc[rr];
  }
}

// ---- K4: agg1 + bias + LN + ReLU, then gemm2 row via LDS bounce -> h2. ----
// 1024 blocks x 256; wave handles 4 nodes.
__global__ __launch_bounds__(256) void agg1_gemm2(const float* __restrict__ h,
    const float* __restrict__ ew, const float* __restrict__ dis,
    const int* __restrict__ knn, const float* __restrict__ bb1,
    const float* __restrict__ gg, const float* __restrict__ gb,
    const float* __restrict__ W2, float* __restrict__ h2){
  __shared__ float Ws[4096];
  __shared__ float rowbuf[4][64];
  int tid=threadIdx.x;
  for(int k=tid;k<4096;k+=256) Ws[k]=W2[k];
  __syncthreads();
  int wave=tid>>6, lane=tid&63;
  int nb=blockIdx.x*16+wave*4;
  for(int r=0;r<4;r++){
    int i=nb+r;
    float di=dis[i];
    float acc=h[i*64+lane]*(di*di);           // self loop, ew=1
    #pragma unroll
    for(int m=0;m<3;m++){
      int s=knn[i*3+m];
      acc+=h[s*64+lane]*(dis[s]*ew[i*3+m]*di);
    }
    acc+=bb1[lane];
    float mu=wsum(acc)*(1.0f/64.0f);
    float dd=acc-mu;
    float var=wsum(dd*dd)*(1.0f/64.0f);
    float y=dd*(1.0f/sqrtf(var+1e-5f))*gg[lane]+gb[lane];
    y=fmaxf(y,0.0f);
    rowbuf[wave][lane]=y;                     // wave-synchronous LDS bounce
    const float4* rb=(const float4*)&rowbuf[wave][0];
    float acc2=0.f;
    #pragma unroll
    for(int k4=0;k4<16;k4++){
      float4 av=rb[k4];                       // broadcast read
      acc2=fmaf(av.x,Ws[(k4*4+0)*64+lane],acc2);
      acc2=fmaf(av.y,Ws[(k4*4+1)*64+lane],acc2);
      acc2=fmaf(av.z,Ws[(k4*4+2)*64+lane],acc2);
      acc2=fmaf(av.w,Ws[(k4*4+3)*64+lane],acc2);
    }
    h2[i*64+lane]=acc2;
  }
}

// ---- K5: second GCN aggregate + bias + residual (out = 2x + gcn2). ----
__global__ __launch_bounds__(256) void agg2_kernel(const float* __restrict__ h2,
    const float* __restrict__ ew, const float* __restrict__ dis,
    const int* __restrict__ knn, const float* __restrict__ bb2,
    const float* __restrict__ x, float* __restrict__ out){
  int wave=threadIdx.x>>6, lane=threadIdx.x&63;
  int i=blockIdx.x*4+wave;
  float di=dis[i];
  float acc=h2[i*64+lane]*(di*di);
  #pragma unroll
  for(int m=0;m<3;m++){
    int s=knn[i*3+m];
    acc+=h2[s*64+lane]*(dis[s]*ew[i*3+m]*di);
  }
  acc+=bb2[lane];
  float xv=x[i*64+lane];
  out[i*64+lane]=(acc+xv)+xv;  // (gcn2 + x) + shortcut, shortcut == x
}

extern "C" void kernel_launch(void* const* d_in, const int* in_sizes, int n_in,
                              void* d_out, int out_size, void* d_ws, size_t ws_size,
                              hipStream_t stream){
  const float* feat  =(const float*)d_in[0];
  // d_in[1] edge_index_tran, d_in[2] edge_attr_rpe, d_in[3] norm_index: unused by reference
  const float* coords=(const float*)d_in[4];
  const float* g1 =(const float*)d_in[5];
  const float* b1n=(const float*)d_in[6];
  const float* g2 =(const float*)d_in[7];
  const float* b2n=(const float*)d_in[8];
  const float* gg =(const float*)d_in[9];
  const float* gb =(const float*)d_in[10];
  const float* W1 =(const float*)d_in[11];
  const float* bb1=(const float*)d_in[12];
  const float* W2 =(const float*)d_in[13];
  const float* bb2=(const float*)d_in[14];
  float* out=(float*)d_out;

  char* ws=(char*)d_ws;
  size_t o=0;
  float*  x      =(float*) (ws+o); o+=(size_t)N*64*4;    // post-LN2 features
  float*  h      =(float*) (ws+o); o+=(size_t)N*64*4;    // gemm1 output
  float*  h2     =(float*) (ws+o); o+=(size_t)N*64*4;    // gemm2 output
  float*  xn     =(float*) (ws+o); o+=(size_t)N*4;       // row norms of x
  float*  ew     =(float*) (ws+o); o+=(size_t)N*3*4;     // knn edge weights
  float*  dis    =(float*) (ws+o); o+=(size_t)N*4;       // 1/sqrt(deg)
  int*    knn    =(int*)   (ws+o); o+=(size_t)N*3*4;     // neighbor indices
  float4* c4     =(float4*)(ws+o); o+=(size_t)N*16;      // (x,y,z,sq) original order
  float4* sc4    =(float4*)(ws+o); o+=(size_t)N*16;      // cell-sorted
  int*    sidx   =(int*)   (ws+o); o+=(size_t)N*4;       // sorted -> original
  int*    cellSt =(int*)   (ws+o); o+=(size_t)(NCELL+1)*4;
  (void)ws_size; (void)in_sizes; (void)n_in; (void)out_size;

  hipLaunchKernelGGL(ln_kernel,    dim3(N/4),  dim3(256), 0, stream, feat,g1,b1n,g2,b2n,coords,x,xn,c4);
  hipLaunchKernelGGL(prep,         dim3(1),    dim3(256), 0, stream, c4,sc4,sidx,cellSt);
  hipLaunchKernelGGL(knn_ew_gemm1, dim3(256),  dim3(256), 0, stream, sc4,sidx,cellSt,c4,x,xn,W1,knn,ew,dis,h);
  hipLaunchKernelGGL(agg1_gemm2,   dim3(N/16), dim3(256), 0, stream, h,ew,dis,knn,bb1,gg,gb,W2,h2);
  hipLaunchKernelGGL(agg2_kernel,  dim3(N/4),  dim3(256), 0, stream, h2,ew,dis,knn,bb2,x,out);
}

// Round 8
// 213.915 us; speedup vs baseline: 2.5583x; 1.4874x over previous
//
#include <hip/hip_runtime.h>
#include <math.h>

#define N 16384
#define GC 8             // grid cells per dim (8 -> margin large enough that fallback ~never fires)
#define NCELL (GC*GC*GC) // 512

__device__ __forceinline__ float wsum(float v){
  #pragma unroll
  for(int m=32;m>0;m>>=1) v += __shfl_xor(v,m,64);
  return v;
}

// branchless lexicographic (d,idx) top-3 insert; matches jax top_k stable tie-break
__device__ __forceinline__ void lexins(float dd,int j2,
    float&D0,float&D1,float&D2,int&I0,int&I1,int&I2){
  bool lt0=(dd<D0)||((dd==D0)&&(j2<I0));
  bool lt1=(dd<D1)||((dd==D1)&&(j2<I1));
  bool lt2=(dd<D2)||((dd==D2)&&(j2<I2));
  float nD2=lt1?D1:(lt2?dd:D2); int nI2=lt1?I1:(lt2?j2:I2);
  float nD1=lt0?D0:(lt1?dd:D1); int nI1=lt0?I0:(lt1?j2:I1);
  float nD0=lt0?dd:D0;          int nI0=lt0?j2:I0;
  D0=nD0;D1=nD1;D2=nD2;I0=nI0;I1=nI1;I2=nI2;
}

// reference-exact squared distance: dd = rn(rn(qs+cs) - 2*dot), dot FMA chain
__device__ __forceinline__ float refdist(float qx,float qy,float qz,float qs,float4 cv){
  float dot=__fmaf_rn(qz,cv.z,__fmaf_rn(qy,cv.y,__fmul_rn(qx,cv.x)));
  float sc =__fadd_rn(qs,cv.w);
  return __fmaf_rn(-2.0f,dot,sc);
}

// ---- K1: LN -> x2 -> LN, row L2 norms, c4=(x,y,z,sq). One wave per row. ----
__global__ __launch_bounds__(256) void ln_kernel(const float* __restrict__ in,
    const float* __restrict__ g1,const float* __restrict__ b1,
    const float* __restrict__ g2,const float* __restrict__ b2,
    const float* __restrict__ coords,
    float* __restrict__ x, float* __restrict__ xn, float4* __restrict__ c4){
  int wave=threadIdx.x>>6, lane=threadIdx.x&63;
  int row=blockIdx.x*4+wave;
  float v=in[row*64+lane];
  float m=wsum(v)*(1.0f/64.0f);
  float d=v-m;
  float var=wsum(d*d)*(1.0f/64.0f);
  float y=d*(1.0f/sqrtf(var+1e-5f))*g1[lane]+b1[lane];
  y=y+y;  // transformer stubbed as identity + shortcut
  float m2=wsum(y)*(1.0f/64.0f);
  float d2=y-m2;
  float var2=wsum(d2*d2)*(1.0f/64.0f);
  float z=d2*(1.0f/sqrtf(var2+1e-5f))*g2[lane]+b2[lane];
  x[row*64+lane]=z;
  float s=wsum(z*z);
  if(lane==0){
    xn[row]=fmaxf(sqrtf(s),1e-8f);
    float a=coords[row*3+0],b=coords[row*3+1],c=coords[row*3+2];
    float sq=__fadd_rn(__fadd_rn(__fmul_rn(a,a),__fmul_rn(b,b)),__fmul_rn(c,c));
    c4[row]=make_float4(a,b,c,sq);
  }
}

// ---- K2: single-block prep: LDS histogram + scan + scatter. ----
__global__ __launch_bounds__(256) void prep(const float4* __restrict__ c4,
    float4* __restrict__ sc4, int* __restrict__ sidx, int* __restrict__ cellSt){
  __shared__ int cnt[NCELL];
  __shared__ int scanbuf[256];
  int tid=threadIdx.x;
  for(int k=tid;k<NCELL;k+=256) cnt[k]=0;
  __syncthreads();
  for(int i=tid;i<N;i+=256){
    float4 v=c4[i];
    int cx=min(GC-1,(int)(v.x*(float)GC)), cy=min(GC-1,(int)(v.y*(float)GC)),
        cz=min(GC-1,(int)(v.z*(float)GC));
    atomicAdd(&cnt[(cz*GC+cy)*GC+cx],1);
  }
  __syncthreads();
  int base=tid*2;
  int c0=cnt[base], c1=cnt[base+1];
  int s=c0+c1;
  scanbuf[tid]=s; __syncthreads();
  for(int off=1;off<256;off<<=1){
    int t=(tid>=off)?scanbuf[tid-off]:0;
    __syncthreads();
    scanbuf[tid]+=t;
    __syncthreads();
  }
  int excl=scanbuf[tid]-s;
  cellSt[base]=excl; cellSt[base+1]=excl+c0;
  cnt[base]=excl;    cnt[base+1]=excl+c0;
  if(tid==255) cellSt[NCELL]=excl+s;
  __syncthreads();
  for(int i=tid;i<N;i+=256){
    float4 v=c4[i];
    int cx=min(GC-1,(int)(v.x*(float)GC)), cy=min(GC-1,(int)(v.y*(float)GC)),
        cz=min(GC-1,(int)(v.z*(float)GC));
    int pos=atomicAdd(&cnt[(cz*GC+cy)*GC+cx],1);
    sc4[pos]=v; sidx[pos]=i;
  }
}

// ---- K3: grid KNN (8 lanes/query, strided within cell runs) + ew + gemm1. ----
// 512 blocks x 256 threads (= N*8 threads, 2 blocks/CU). Each wave owns 8
// sorted slots: KNN them, then edge-weights (knn via shuffles), then gemm1.
__global__ __launch_bounds__(256) void knn_ew_gemm1(const float4* __restrict__ sc4,
    const int* __restrict__ sidx, const int* __restrict__ cellSt,
    const float4* __restrict__ c4, const float* __restrict__ x,
    const float* __restrict__ xn, const float* __restrict__ W1,
    int* __restrict__ knn, float* __restrict__ ew, float* __restrict__ dis,
    float* __restrict__ h){
  __shared__ float Ws[4096];
  int tid=threadIdx.x, bid=blockIdx.x;
  for(int k=tid;k<4096;k+=256) Ws[k]=W1[k];    // staged for gemm phase
  int gt=bid*256+tid;
  int lane=tid&63;
  int slot=gt>>3, part=tid&7;

  // --- KNN: 8 lanes stride by 8 within each of the 9 x-merged cell runs ---
  float4 qv=sc4[slot]; int q=sidx[slot];
  float qx=qv.x,qy=qv.y,qz=qv.z,qs=qv.w;
  int cx=min(GC-1,(int)(qx*(float)GC)), cy=min(GC-1,(int)(qy*(float)GC)),
      cz=min(GC-1,(int)(qz*(float)GC));
  float D0=1e30f,D1=1e30f,D2=1e30f; int I0=0x7fffffff,I1=0x7fffffff,I2=0x7fffffff;
  int xlo=max(cx-1,0), xhi=min(cx+1,GC-1);
  for(int r=0;r<9;r++){
    int z2=cz+r/3-1, y2=cy+r%3-1;
    if(z2<0||z2>=GC||y2<0||y2>=GC) continue;
    int rowb=(z2*GC+y2)*GC;
    int p0=cellSt[rowb+xlo], p1=cellSt[rowb+xhi+1];  // x-cells contiguous
    for(int p=p0+part;p<p1;p+=8){
      float4 cv=sc4[p]; int j2=sidx[p];
      float dd=refdist(qx,qy,qz,qs,cv);
      dd=(j2==q)?1e30f:dd;
      lexins(dd,j2,D0,D1,D2,I0,I1,I2);
    }
  }
  #pragma unroll
  for(int m=1;m<8;m<<=1){
    float e0=__shfl_xor(D0,m),e1=__shfl_xor(D1,m),e2=__shfl_xor(D2,m);
    int   f0=__shfl_xor(I0,m),f1=__shfl_xor(I1,m),f2=__shfl_xor(I2,m);
    lexins(e0,f0,D0,D1,D2,I0,I1,I2);
    lexins(e1,f1,D0,D1,D2,I0,I1,I2);
    lexins(e2,f2,D0,D1,D2,I0,I1,I2);
  }
  bool flg=false;
  if(part==0){
    const float cw=1.0f/(float)GC;
    float mg=1e30f;
    mg=fminf(mg,(cx>0)?(qx-(float)(cx-1)*cw):1e30f);
    mg=fminf(mg,(cx<GC-1)?((float)(cx+2)*cw-qx):1e30f);
    mg=fminf(mg,(cy>0)?(qy-(float)(cy-1)*cw):1e30f);
    mg=fminf(mg,(cy<GC-1)?((float)(cy+2)*cw-qy):1e30f);
    mg=fminf(mg,(cz>0)?(qz-(float)(cz-1)*cw):1e30f);
    mg=fminf(mg,(cz<GC-1)?((float)(cz+2)*cw-qz):1e30f);
    float mg2=mg*mg*(1.0f-1e-5f);   // slack for dd rounding
    flg=!(D2<mg2);                  // at GC=8: ~never true (margin >= 1/8)
  }
  // safety-net fallback, expected 0 queries
  unsigned long long mask=__ballot(flg);
  while(mask){
    int b=__ffsll((unsigned long long)mask)-1; mask&=mask-1;
    int qb=__shfl(q,b);
    float bx=__shfl(qx,b),by=__shfl(qy,b),bz=__shfl(qz,b),bs=__shfl(qs,b);
    float E0=1e30f,E1=1e30f,E2=1e30f; int F0=0x7fffffff,F1=0x7fffffff,F2=0x7fffffff;
    for(int j=lane;j<N;j+=64){
      float4 cv=c4[j];
      float dd=refdist(bx,by,bz,bs,cv);
      dd=(j==qb)?1e30f:dd;
      lexins(dd,j,E0,E1,E2,F0,F1,F2);
    }
    #pragma unroll
    for(int m=1;m<64;m<<=1){
      float e0=__shfl_xor(E0,m),e1=__shfl_xor(E1,m),e2=__shfl_xor(E2,m);
      int   f0=__shfl_xor(F0,m),f1=__shfl_xor(F1,m),f2=__shfl_xor(F2,m);
      lexins(e0,f0,E0,E1,E2,F0,F1,F2);
      lexins(e1,f1,E0,E1,E2,F0,F1,F2);
      lexins(e2,f2,E0,E1,E2,F0,F1,F2);
    }
    if(lane==b){ I0=F0; I1=F1; I2=F2; }
  }
  if(part==0){ knn[q*3+0]=I0; knn[q*3+1]=I1; knn[q*3+2]=I2; }

  // --- ew + dis for the wave's 8 queries (neighbor loads hoisted) ---
  int qrow[8];
  for(int r=0;r<8;r++){
    int qi=__shfl(q,8*r);
    int s0=__shfl(I0,8*r), s1=__shfl(I1,8*r), s2=__shfl(I2,8*r);
    qrow[r]=qi;
    float xi=x[qi*64+lane];
    float xs0=x[s0*64+lane], xs1=x[s1*64+lane], xs2=x[s2*64+lane];
    float n0=xn[s0], n1=xn[s1], n2=xn[s2];
    float ni=xn[qi];
    float dt0=wsum(xs0*xi), dt1=wsum(xs1*xi), dt2=wsum(xs2*xi);
    float e0=1.f/(1.f+expf(-(dt0/(n0*ni))));
    float e1=1.f/(1.f+expf(-(dt1/(n1*ni))));
    float e2=1.f/(1.f+expf(-(dt2/(n2*ni))));
    if(lane==0){
      ew[qi*3+0]=e0; ew[qi*3+1]=e1; ew[qi*3+2]=e2;
      float ssum=((e0+e1)+e2);                  // same assoc as loop version
      dis[qi]=1.f/sqrtf(ssum+1.0f);             // deg = 1 (self loop) + sum(ew)
    }
  }

  // --- gemm1: h[row] = x[row] @ W1 for the wave's 8 rows ---
  __syncthreads();                       // Ws ready
  const float4* X4=(const float4*)x;
  for(int rg=0;rg<2;rg++){
    float acc[4]={0.f,0.f,0.f,0.f};
    #pragma unroll
    for(int k4=0;k4<16;k4++){
      float w0=Ws[(k4*4+0)*64+lane];
      float w1=Ws[(k4*4+1)*64+lane];
      float w2=Ws[(k4*4+2)*64+lane];
      float w3=Ws[(k4*4+3)*64+lane];
      #pragma unroll
      for(int rr=0;rr<4;rr++){
        float4 xv=X4[qrow[rg*4+rr]*16+k4];
        acc[rr]=fmaf(xv.x,w0,acc[rr]);
        acc[rr]=fmaf(xv.y,w1,acc[rr]);
        acc[rr]=fmaf(xv.z,w2,acc[rr]);
        acc[rr]=fmaf(xv.w,w3,acc[rr]);
      }
    }
    #pragma unroll
    for(int rr=0;rr<4;rr++) h[qrow[rg*4+rr]*64+lane]=acc[rr];
  }
}

// ---- K4: agg1 + bias + LN + ReLU, then gemm2 row via LDS bounce -> h2. ----
__global__ __launch_bounds__(256) void agg1_gemm2(const float* __restrict__ h,
    const float* __restrict__ ew, const float* __restrict__ dis,
    const int* __restrict__ knn, const float* __restrict__ bb1,
    const float* __restrict__ gg, const float* __restrict__ gb,
    const float* __restrict__ W2, float* __restrict__ h2){
  __shared__ float Ws[4096];
  __shared__ float rowbuf[4][64];
  int tid=threadIdx.x;
  for(int k=tid;k<4096;k+=256) Ws[k]=W2[k];
  __syncthreads();
  int wave=tid>>6, lane=tid&63;
  int nb=blockIdx.x*16+wave*4;
  for(int r=0;r<4;r++){
    int i=nb+r;
    float di=dis[i];
    float acc=h[i*64+lane]*(di*di);           // self loop, ew=1
    #pragma unroll
    for(int m=0;m<3;m++){
      int s=knn[i*3+m];
      acc+=h[s*64+lane]*(dis[s]*ew[i*3+m]*di);
    }
    acc+=bb1[lane];
    float mu=wsum(acc)*(1.0f/64.0f);
    float dd=acc-mu;
    float var=wsum(dd*dd)*(1.0f/64.0f);
    float y=dd*(1.0f/sqrtf(var+1e-5f))*gg[lane]+gb[lane];
    y=fmaxf(y,0.0f);
    rowbuf[wave][lane]=y;                     // wave-synchronous LDS bounce
    const float4* rb=(const float4*)&rowbuf[wave][0];
    float acc2=0.f;
    #pragma unroll
    for(int k4=0;k4<16;k4++){
      float4 av=rb[k4];                       // broadcast read
      acc2=fmaf(av.x,Ws[(k4*4+0)*64+lane],acc2);
      acc2=fmaf(av.y,Ws[(k4*4+1)*64+lane],acc2);
      acc2=fmaf(av.z,Ws[(k4*4+2)*64+lane],acc2);
      acc2=fmaf(av.w,Ws[(k4*4+3)*64+lane],acc2);
    }
    h2[i*64+lane]=acc2;
  }
}

// ---- K5: second GCN aggregate + bias + residual (out = 2x + gcn2). ----
__global__ __launch_bounds__(256) void agg2_kernel(const float* __restrict__ h2,
    const float* __restrict__ ew, const float* __restrict__ dis,
    const int* __restrict__ knn, const float* __restrict__ bb2,
    const float* __restrict__ x, float* __restrict__ out){
  int wave=threadIdx.x>>6, lane=threadIdx.x&63;
  int i=blockIdx.x*4+wave;
  float di=dis[i];
  float acc=h2[i*64+lane]*(di*di);
  #pragma unroll
  for(int m=0;m<3;m++){
    int s=knn[i*3+m];
    acc+=h2[s*64+lane]*(dis[s]*ew[i*3+m]*di);
  }
  acc+=bb2[lane];
  float xv=x[i*64+lane];
  out[i*64+lane]=(acc+xv)+xv;  // (gcn2 + x) + shortcut, shortcut == x
}

extern "C" void kernel_launch(void* const* d_in, const int* in_sizes, int n_in,
                              void* d_out, int out_size, void* d_ws, size_t ws_size,
                              hipStream_t stream){
  const float* feat  =(const float*)d_in[0];
  // d_in[1] edge_index_tran, d_in[2] edge_attr_rpe, d_in[3] norm_index: unused by reference
  const float* coords=(const float*)d_in[4];
  const float* g1 =(const float*)d_in[5];
  const float* b1n=(const float*)d_in[6];
  const float* g2 =(const float*)d_in[7];
  const float* b2n=(const float*)d_in[8];
  const float* gg =(const float*)d_in[9];
  const float* gb =(const float*)d_in[10];
  const float* W1 =(const float*)d_in[11];
  const float* bb1=(const float*)d_in[12];
  const float* W2 =(const float*)d_in[13];
  const float* bb2=(const float*)d_in[14];
  float* out=(float*)d_out;

  char* ws=(char*)d_ws;
  size_t o=0;
  float*  x      =(float*) (ws+o); o+=(size_t)N*64*4;    // post-LN2 features
  float*  h      =(float*) (ws+o); o+=(size_t)N*64*4;    // gemm1 output
  float*  h2     =(float*) (ws+o); o+=(size_t)N*64*4;    // gemm2 output
  float*  xn     =(float*) (ws+o); o+=(size_t)N*4;       // row norms of x
  float*  ew     =(float*) (ws+o); o+=(size_t)N*3*4;     // knn edge weights
  float*  dis    =(float*) (ws+o); o+=(size_t)N*4;       // 1/sqrt(deg)
  int*    knn    =(int*)   (ws+o); o+=(size_t)N*3*4;     // neighbor indices
  float4* c4     =(float4*)(ws+o); o+=(size_t)N*16;      // (x,y,z,sq) original order
  float4* sc4    =(float4*)(ws+o); o+=(size_t)N*16;      // cell-sorted
  int*    sidx   =(int*)   (ws+o); o+=(size_t)N*4;       // sorted -> original
  int*    cellSt =(int*)   (ws+o); o+=(size_t)(NCELL+1)*4;
  (void)ws_size; (void)in_sizes; (void)n_in; (void)out_size;

  hipLaunchKernelGGL(ln_kernel,    dim3(N/4),  dim3(256), 0, stream, feat,g1,b1n,g2,b2n,coords,x,xn,c4);
  hipLaunchKernelGGL(prep,         dim3(1),    dim3(256), 0, stream, c4,sc4,sidx,cellSt);
  hipLaunchKernelGGL(knn_ew_gemm1, dim3(512),  dim3(256), 0, stream, sc4,sidx,cellSt,c4,x,xn,W1,knn,ew,dis,h);
  hipLaunchKernelGGL(agg1_gemm2,   dim3(N/16), dim3(256), 0, stream, h,ew,dis,knn,bb1,gg,gb,W2,h2);
  hipLaunchKernelGGL(agg2_kernel,  dim3(N/4),  dim3(256), 0, stream, h2,ew,dis,knn,bb2,x,out);
}

// Round 9
// 178.324 us; speedup vs baseline: 3.0690x; 1.1996x over previous
//
#include <hip/hip_runtime.h>
#include <math.h>

#define N 16384
#define GC 8             // grid cells per dim (margin >= 1/8 -> fallback ~never fires)
#define NCELL (GC*GC*GC) // 512

__device__ __forceinline__ float wsum(float v){
  #pragma unroll
  for(int m=32;m>0;m>>=1) v += __shfl_xor(v,m,64);
  return v;
}

// branchless lexicographic (d,idx) top-3 insert; matches jax top_k stable tie-break
__device__ __forceinline__ void lexins(float dd,int j2,
    float&D0,float&D1,float&D2,int&I0,int&I1,int&I2){
  bool lt0=(dd<D0)||((dd==D0)&&(j2<I0));
  bool lt1=(dd<D1)||((dd==D1)&&(j2<I1));
  bool lt2=(dd<D2)||((dd==D2)&&(j2<I2));
  float nD2=lt1?D1:(lt2?dd:D2); int nI2=lt1?I1:(lt2?j2:I2);
  float nD1=lt0?D0:(lt1?dd:D1); int nI1=lt0?I0:(lt1?j2:I1);
  float nD0=lt0?dd:D0;          int nI0=lt0?j2:I0;
  D0=nD0;D1=nD1;D2=nD2;I0=nI0;I1=nI1;I2=nI2;
}

// reference-exact squared distance: dd = rn(rn(qs+cs) - 2*dot), dot FMA chain
__device__ __forceinline__ float refdist(float qx,float qy,float qz,float qs,float4 cv){
  float dot=__fmaf_rn(qz,cv.z,__fmaf_rn(qy,cv.y,__fmul_rn(qx,cv.x)));
  float sc =__fadd_rn(qs,cv.w);
  return __fmaf_rn(-2.0f,dot,sc);
}

// ---- K1: LN -> x2 -> LN, row L2 norms, c4=(x,y,z,sq). One wave per row. ----
__global__ __launch_bounds__(256) void ln_kernel(const float* __restrict__ in,
    const float* __restrict__ g1,const float* __restrict__ b1,
    const float* __restrict__ g2,const float* __restrict__ b2,
    const float* __restrict__ coords,
    float* __restrict__ x, float* __restrict__ xn, float4* __restrict__ c4){
  int wave=threadIdx.x>>6, lane=threadIdx.x&63;
  int row=blockIdx.x*4+wave;
  float v=in[row*64+lane];
  float m=wsum(v)*(1.0f/64.0f);
  float d=v-m;
  float var=wsum(d*d)*(1.0f/64.0f);
  float y=d*(1.0f/sqrtf(var+1e-5f))*g1[lane]+b1[lane];
  y=y+y;  // transformer stubbed as identity + shortcut
  float m2=wsum(y)*(1.0f/64.0f);
  float d2=y-m2;
  float var2=wsum(d2*d2)*(1.0f/64.0f);
  float z=d2*(1.0f/sqrtf(var2+1e-5f))*g2[lane]+b2[lane];
  x[row*64+lane]=z;
  float s=wsum(z*z);
  if(lane==0){
    xn[row]=fmaxf(sqrtf(s),1e-8f);
    float a=coords[row*3+0],b=coords[row*3+1],c=coords[row*3+2];
    float sq=__fadd_rn(__fadd_rn(__fmul_rn(a,a),__fmul_rn(b,b)),__fmul_rn(c,c));
    c4[row]=make_float4(a,b,c,sq);
  }
}

// ---- K2: single-block prep (1024 threads): LDS histogram + scan + scatter. ----
__global__ __launch_bounds__(1024) void prep(const float4* __restrict__ c4,
    float4* __restrict__ sc4, int* __restrict__ sidx, int* __restrict__ cellSt){
  __shared__ int cnt[NCELL];
  __shared__ int scanbuf[NCELL];
  int tid=threadIdx.x;
  if(tid<NCELL) cnt[tid]=0;
  __syncthreads();
  for(int i=tid;i<N;i+=1024){
    float4 v=c4[i];
    int cx=min(GC-1,(int)(v.x*(float)GC)), cy=min(GC-1,(int)(v.y*(float)GC)),
        cz=min(GC-1,(int)(v.z*(float)GC));
    atomicAdd(&cnt[(cz*GC+cy)*GC+cx],1);
  }
  __syncthreads();
  if(tid<NCELL) scanbuf[tid]=cnt[tid];
  __syncthreads();
  for(int off=1;off<NCELL;off<<=1){
    int t=0;
    if(tid>=off && tid<NCELL) t=scanbuf[tid-off];
    __syncthreads();
    if(tid<NCELL) scanbuf[tid]+=t;
    __syncthreads();
  }
  if(tid<NCELL){
    int excl=scanbuf[tid]-cnt[tid];
    cellSt[tid]=excl; cnt[tid]=excl;
    if(tid==NCELL-1) cellSt[NCELL]=scanbuf[NCELL-1];
  }
  __syncthreads();
  for(int i=tid;i<N;i+=1024){
    float4 v=c4[i];
    int cx=min(GC-1,(int)(v.x*(float)GC)), cy=min(GC-1,(int)(v.y*(float)GC)),
        cz=min(GC-1,(int)(v.z*(float)GC));
    int pos=atomicAdd(&cnt[(cz*GC+cy)*GC+cx],1);
    sc4[pos]=v; sidx[pos]=i;
  }
}

// ---- K3: grid KNN (16 lanes/query) + edge weights. 1024 blocks x 256. ----
// 4 queries per wave; 16 lanes stride the 9 x-merged cell runs; 4-step
// butterfly merge. No gemm here (moved to K4/K5 via agg/gemm commutation).
__global__ __launch_bounds__(256) void knn_ew(const float4* __restrict__ sc4,
    const int* __restrict__ sidx, const int* __restrict__ cellSt,
    const float4* __restrict__ c4, const float* __restrict__ x,
    const float* __restrict__ xn,
    int* __restrict__ knn, float* __restrict__ ew, float* __restrict__ dis){
  int tid=threadIdx.x, bid=blockIdx.x;
  int gt=bid*256+tid;
  int lane=tid&63;
  int slot=gt>>4, part=tid&15;

  // --- KNN: numerics identical to r5-r8 ---
  float4 qv=sc4[slot]; int q=sidx[slot];
  float qx=qv.x,qy=qv.y,qz=qv.z,qs=qv.w;
  int cx=min(GC-1,(int)(qx*(float)GC)), cy=min(GC-1,(int)(qy*(float)GC)),
      cz=min(GC-1,(int)(qz*(float)GC));
  float D0=1e30f,D1=1e30f,D2=1e30f; int I0=0x7fffffff,I1=0x7fffffff,I2=0x7fffffff;
  int xlo=max(cx-1,0), xhi=min(cx+1,GC-1);
  for(int r=0;r<9;r++){
    int z2=cz+r/3-1, y2=cy+r%3-1;
    if(z2<0||z2>=GC||y2<0||y2>=GC) continue;
    int rowb=(z2*GC+y2)*GC;
    int p0=cellSt[rowb+xlo], p1=cellSt[rowb+xhi+1];  // x-cells contiguous
    for(int p=p0+part;p<p1;p+=16){
      float4 cv=sc4[p]; int j2=sidx[p];
      float dd=refdist(qx,qy,qz,qs,cv);
      dd=(j2==q)?1e30f:dd;
      lexins(dd,j2,D0,D1,D2,I0,I1,I2);
    }
  }
  #pragma unroll
  for(int m=1;m<16;m<<=1){
    float e0=__shfl_xor(D0,m),e1=__shfl_xor(D1,m),e2=__shfl_xor(D2,m);
    int   f0=__shfl_xor(I0,m),f1=__shfl_xor(I1,m),f2=__shfl_xor(I2,m);
    lexins(e0,f0,D0,D1,D2,I0,I1,I2);
    lexins(e1,f1,D0,D1,D2,I0,I1,I2);
    lexins(e2,f2,D0,D1,D2,I0,I1,I2);
  }
  bool flg=false;
  if(part==0){
    const float cw=1.0f/(float)GC;
    float mg=1e30f;
    mg=fminf(mg,(cx>0)?(qx-(float)(cx-1)*cw):1e30f);
    mg=fminf(mg,(cx<GC-1)?((float)(cx+2)*cw-qx):1e30f);
    mg=fminf(mg,(cy>0)?(qy-(float)(cy-1)*cw):1e30f);
    mg=fminf(mg,(cy<GC-1)?((float)(cy+2)*cw-qy):1e30f);
    mg=fminf(mg,(cz>0)?(qz-(float)(cz-1)*cw):1e30f);
    mg=fminf(mg,(cz<GC-1)?((float)(cz+2)*cw-qz):1e30f);
    float mg2=mg*mg*(1.0f-1e-5f);   // slack for dd rounding
    flg=!(D2<mg2);                  // at GC=8: ~never true
  }
  // safety-net fallback, expected ~0 queries
  unsigned long long mask=__ballot(flg);
  while(mask){
    int b=__ffsll((unsigned long long)mask)-1; mask&=mask-1;
    int qb=__shfl(q,b);
    float bx=__shfl(qx,b),by=__shfl(qy,b),bz=__shfl(qz,b),bs=__shfl(qs,b);
    float E0=1e30f,E1=1e30f,E2=1e30f; int F0=0x7fffffff,F1=0x7fffffff,F2=0x7fffffff;
    for(int j=lane;j<N;j+=64){
      float4 cv=c4[j];
      float dd=refdist(bx,by,bz,bs,cv);
      dd=(j==qb)?1e30f:dd;
      lexins(dd,j,E0,E1,E2,F0,F1,F2);
    }
    #pragma unroll
    for(int m=1;m<64;m<<=1){
      float e0=__shfl_xor(E0,m),e1=__shfl_xor(E1,m),e2=__shfl_xor(E2,m);
      int   f0=__shfl_xor(F0,m),f1=__shfl_xor(F1,m),f2=__shfl_xor(F2,m);
      lexins(e0,f0,E0,E1,E2,F0,F1,F2);
      lexins(e1,f1,E0,E1,E2,F0,F1,F2);
      lexins(e2,f2,E0,E1,E2,F0,F1,F2);
    }
    if(lane==b){ I0=F0; I1=F1; I2=F2; }
  }
  if(part==0){ knn[q*3+0]=I0; knn[q*3+1]=I1; knn[q*3+2]=I2; }

  // --- ew + dis for the wave's 4 queries (neighbor loads hoisted) ---
  for(int r=0;r<4;r++){
    int qi=__shfl(q,16*r);
    int s0=__shfl(I0,16*r), s1=__shfl(I1,16*r), s2=__shfl(I2,16*r);
    float xi=x[qi*64+lane];
    float xs0=x[s0*64+lane], xs1=x[s1*64+lane], xs2=x[s2*64+lane];
    float n0=xn[s0], n1=xn[s1], n2=xn[s2];
    float ni=xn[qi];
    float dt0=wsum(xs0*xi), dt1=wsum(xs1*xi), dt2=wsum(xs2*xi);
    float e0=1.f/(1.f+expf(-(dt0/(n0*ni))));
    float e1=1.f/(1.f+expf(-(dt1/(n1*ni))));
    float e2=1.f/(1.f+expf(-(dt2/(n2*ni))));
    if(lane==0){
      ew[qi*3+0]=e0; ew[qi*3+1]=e1; ew[qi*3+2]=e2;
      float ssum=((e0+e1)+e2);
      dis[qi]=1.f/sqrtf(ssum+1.0f);             // deg = 1 (self loop) + sum(ew)
    }
  }
}

// ---- K4: xa = weighted-agg(x); a1 = relu(LN(xa@W1 + b1)). Wave per 4 nodes. ----
// Uses agg/gemm commutation: segment_sum(norm * (x@W)[src]) == (segment_sum(norm*x[src]))@W.
__global__ __launch_bounds__(256) void agg1_w1(const float* __restrict__ x,
    const float* __restrict__ ew, const float* __restrict__ dis,
    const int* __restrict__ knn, const float* __restrict__ W1,
    const float* __restrict__ bb1, const float* __restrict__ gg,
    const float* __restrict__ gb, float* __restrict__ a1){
  __shared__ float Ws[4096];
  __shared__ float rowbuf[4][64];
  int tid=threadIdx.x;
  for(int k=tid;k<4096;k+=256) Ws[k]=W1[k];
  __syncthreads();
  int wave=tid>>6, lane=tid&63;
  int nb=blockIdx.x*16+wave*4;
  for(int r=0;r<4;r++){
    int i=nb+r;
    float di=dis[i];
    float xa=x[i*64+lane]*(di*di);            // self loop, ew=1
    #pragma unroll
    for(int m=0;m<3;m++){
      int s=knn[i*3+m];
      xa+=x[s*64+lane]*(dis[s]*ew[i*3+m]*di);
    }
    rowbuf[wave][lane]=xa;                    // wave-synchronous LDS bounce
    const float4* rb=(const float4*)&rowbuf[wave][0];
    float acc=0.f;
    #pragma unroll
    for(int k4=0;k4<16;k4++){
      float4 av=rb[k4];                       // broadcast read
      acc=fmaf(av.x,Ws[(k4*4+0)*64+lane],acc);
      acc=fmaf(av.y,Ws[(k4*4+1)*64+lane],acc);
      acc=fmaf(av.z,Ws[(k4*4+2)*64+lane],acc);
      acc=fmaf(av.w,Ws[(k4*4+3)*64+lane],acc);
    }
    acc+=bb1[lane];
    float mu=wsum(acc)*(1.0f/64.0f);
    float dd=acc-mu;
    float var=wsum(dd*dd)*(1.0f/64.0f);
    float y=dd*(1.0f/sqrtf(var+1e-5f))*gg[lane]+gb[lane];
    a1[i*64+lane]=fmaxf(y,0.0f);
  }
}

// ---- K5: aa = weighted-agg(a1); out = aa@W2 + b2 + 2x. Wave per 4 nodes. ----
__global__ __launch_bounds__(256) void agg2_w2(const float* __restrict__ a1,
    const float* __restrict__ ew, const float* __restrict__ dis,
    const int* __restrict__ knn, const float* __restrict__ W2,
    const float* __restrict__ bb2, const float* __restrict__ x,
    float* __restrict__ out){
  __shared__ float Ws[4096];
  __shared__ float rowbuf[4][64];
  int tid=threadIdx.x;
  for(int k=tid;k<4096;k+=256) Ws[k]=W2[k];
  __syncthreads();
  int wave=tid>>6, lane=tid&63;
  int nb=blockIdx.x*16+wave*4;
  for(int r=0;r<4;r++){
    int i=nb+r;
    float di=dis[i];
    float aa=a1[i*64+lane]*(di*di);
    #pragma unroll
    for(int m=0;m<3;m++){
      int s=knn[i*3+m];
      aa+=a1[s*64+lane]*(dis[s]*ew[i*3+m]*di);
    }
    rowbuf[wave][lane]=aa;
    const float4* rb=(const float4*)&rowbuf[wave][0];
    float acc=0.f;
    #pragma unroll
    for(int k4=0;k4<16;k4++){
      float4 av=rb[k4];
      acc=fmaf(av.x,Ws[(k4*4+0)*64+lane],acc);
      acc=fmaf(av.y,Ws[(k4*4+1)*64+lane],acc);
      acc=fmaf(av.z,Ws[(k4*4+2)*64+lane],acc);
      acc=fmaf(av.w,Ws[(k4*4+3)*64+lane],acc);
    }
    acc+=bb2[lane];
    float xv=x[i*64+lane];
    out[i*64+lane]=(acc+xv)+xv;  // (gcn2 + x) + shortcut, shortcut == x
  }
}

extern "C" void kernel_launch(void* const* d_in, const int* in_sizes, int n_in,
                              void* d_out, int out_size, void* d_ws, size_t ws_size,
                              hipStream_t stream){
  const float* feat  =(const float*)d_in[0];
  // d_in[1] edge_index_tran, d_in[2] edge_attr_rpe, d_in[3] norm_index: unused by reference
  const float* coords=(const float*)d_in[4];
  const float* g1 =(const float*)d_in[5];
  const float* b1n=(const float*)d_in[6];
  const float* g2 =(const float*)d_in[7];
  const float* b2n=(const float*)d_in[8];
  const float* gg =(const float*)d_in[9];
  const float* gb =(const float*)d_in[10];
  const float* W1 =(const float*)d_in[11];
  const float* bb1=(const float*)d_in[12];
  const float* W2 =(const float*)d_in[13];
  const float* bb2=(const float*)d_in[14];
  float* out=(float*)d_out;

  char* ws=(char*)d_ws;
  size_t o=0;
  float*  x      =(float*) (ws+o); o+=(size_t)N*64*4;    // post-LN2 features
  float*  a1     =(float*) (ws+o); o+=(size_t)N*64*4;    // activated GCN1 output
  float*  xn     =(float*) (ws+o); o+=(size_t)N*4;       // row norms of x
  float*  ew     =(float*) (ws+o); o+=(size_t)N*3*4;     // knn edge weights
  float*  dis    =(float*) (ws+o); o+=(size_t)N*4;       // 1/sqrt(deg)
  int*    knn    =(int*)   (ws+o); o+=(size_t)N*3*4;     // neighbor indices
  float4* c4     =(float4*)(ws+o); o+=(size_t)N*16;      // (x,y,z,sq) original order
  float4* sc4    =(float4*)(ws+o); o+=(size_t)N*16;      // cell-sorted
  int*    sidx   =(int*)   (ws+o); o+=(size_t)N*4;       // sorted -> original
  int*    cellSt =(int*)   (ws+o); o+=(size_t)(NCELL+1)*4;
  (void)ws_size; (void)in_sizes; (void)n_in; (void)out_size;

  hipLaunchKernelGGL(ln_kernel, dim3(N/4),  dim3(256),  0, stream, feat,g1,b1n,g2,b2n,coords,x,xn,c4);
  hipLaunchKernelGGL(prep,      dim3(1),    dim3(1024), 0, stream, c4,sc4,sidx,cellSt);
  hipLaunchKernelGGL(knn_ew,    dim3(1024), dim3(256),  0, stream, sc4,sidx,cellSt,c4,x,xn,knn,ew,dis);
  hipLaunchKernelGGL(agg1_w1,   dim3(N/16), dim3(256),  0, stream, x,ew,dis,knn,W1,bb1,gg,gb,a1);
  hipLaunchKernelGGL(agg2_w2,   dim3(N/16), dim3(256),  0, stream, a1,ew,dis,knn,W2,bb2,x,out);
}

// Round 10
// 167.156 us; speedup vs baseline: 3.2740x; 1.0668x over previous
//
#include <hip/hip_runtime.h>
#include <math.h>

#define N 16384
#define GC 8             // grid cells per dim (margin >= 1/8 -> fallback ~never fires)
#define NCELL (GC*GC*GC) // 512

__device__ __forceinline__ float wsum(float v){
  #pragma unroll
  for(int m=32;m>0;m>>=1) v += __shfl_xor(v,m,64);
  return v;
}

// branchless lexicographic (d,idx) top-3 insert; matches jax top_k stable tie-break
__device__ __forceinline__ void lexins(float dd,int j2,
    float&D0,float&D1,float&D2,int&I0,int&I1,int&I2){
  bool lt0=(dd<D0)||((dd==D0)&&(j2<I0));
  bool lt1=(dd<D1)||((dd==D1)&&(j2<I1));
  bool lt2=(dd<D2)||((dd==D2)&&(j2<I2));
  float nD2=lt1?D1:(lt2?dd:D2); int nI2=lt1?I1:(lt2?j2:I2);
  float nD1=lt0?D0:(lt1?dd:D1); int nI1=lt0?I0:(lt1?j2:I1);
  float nD0=lt0?dd:D0;          int nI0=lt0?j2:I0;
  D0=nD0;D1=nD1;D2=nD2;I0=nI0;I1=nI1;I2=nI2;
}

// reference-exact squared distance: dd = rn(rn(qs+cs) - 2*dot), dot FMA chain
__device__ __forceinline__ float refdist(float qx,float qy,float qz,float qs,float4 cv){
  float dot=__fmaf_rn(qz,cv.z,__fmaf_rn(qy,cv.y,__fmul_rn(qx,cv.x)));
  float sc =__fadd_rn(qs,cv.w);
  return __fmaf_rn(-2.0f,dot,sc);
}

// ---- K1: LN -> x2 -> LN, row L2 norms, c4=(x,y,z,sq). One wave per row. ----
__global__ __launch_bounds__(256) void ln_kernel(const float* __restrict__ in,
    const float* __restrict__ g1,const float* __restrict__ b1,
    const float* __restrict__ g2,const float* __restrict__ b2,
    const float* __restrict__ coords,
    float* __restrict__ x, float* __restrict__ xn, float4* __restrict__ c4){
  int wave=threadIdx.x>>6, lane=threadIdx.x&63;
  int row=blockIdx.x*4+wave;
  float v=in[row*64+lane];
  float m=wsum(v)*(1.0f/64.0f);
  float d=v-m;
  float var=wsum(d*d)*(1.0f/64.0f);
  float y=d*(1.0f/sqrtf(var+1e-5f))*g1[lane]+b1[lane];
  y=y+y;  // transformer stubbed as identity + shortcut
  float m2=wsum(y)*(1.0f/64.0f);
  float d2=y-m2;
  float var2=wsum(d2*d2)*(1.0f/64.0f);
  float z=d2*(1.0f/sqrtf(var2+1e-5f))*g2[lane]+b2[lane];
  x[row*64+lane]=z;
  float s=wsum(z*z);
  if(lane==0){
    xn[row]=fmaxf(sqrtf(s),1e-8f);
    float a=coords[row*3+0],b=coords[row*3+1],c=coords[row*3+2];
    float sq=__fadd_rn(__fadd_rn(__fmul_rn(a,a),__fmul_rn(b,b)),__fmul_rn(c,c));
    c4[row]=make_float4(a,b,c,sq);
  }
}

// ---- K2: single-block prep (1024 threads): LDS histogram + scan + scatter. ----
__global__ __launch_bounds__(1024) void prep(const float4* __restrict__ c4,
    float4* __restrict__ sc4, int* __restrict__ sidx, int* __restrict__ cellSt){
  __shared__ int cnt[NCELL];
  __shared__ int scanbuf[NCELL];
  int tid=threadIdx.x;
  if(tid<NCELL) cnt[tid]=0;
  __syncthreads();
  for(int i=tid;i<N;i+=1024){
    float4 v=c4[i];
    int cx=min(GC-1,(int)(v.x*(float)GC)), cy=min(GC-1,(int)(v.y*(float)GC)),
        cz=min(GC-1,(int)(v.z*(float)GC));
    atomicAdd(&cnt[(cz*GC+cy)*GC+cx],1);
  }
  __syncthreads();
  if(tid<NCELL) scanbuf[tid]=cnt[tid];
  __syncthreads();
  for(int off=1;off<NCELL;off<<=1){
    int t=0;
    if(tid>=off && tid<NCELL) t=scanbuf[tid-off];
    __syncthreads();
    if(tid<NCELL) scanbuf[tid]+=t;
    __syncthreads();
  }
  if(tid<NCELL){
    int excl=scanbuf[tid]-cnt[tid];
    cellSt[tid]=excl; cnt[tid]=excl;
    if(tid==NCELL-1) cellSt[NCELL]=scanbuf[NCELL-1];
  }
  __syncthreads();
  for(int i=tid;i<N;i+=1024){
    float4 v=c4[i];
    int cx=min(GC-1,(int)(v.x*(float)GC)), cy=min(GC-1,(int)(v.y*(float)GC)),
        cz=min(GC-1,(int)(v.z*(float)GC));
    int pos=atomicAdd(&cnt[(cz*GC+cy)*GC+cx],1);
    sc4[pos]=v; sidx[pos]=i;
  }
}

// ---- K3: grid KNN (32 lanes/query) + edge weights. 2048 blocks x 256. ----
// 2 queries per wave; 32 lanes stride the 9 x-merged cell runs; 5-step
// butterfly merge (stays within the 32-lane group). 8 blocks/CU = 32 waves/CU.
__global__ __launch_bounds__(256) void knn_ew(const float4* __restrict__ sc4,
    const int* __restrict__ sidx, const int* __restrict__ cellSt,
    const float4* __restrict__ c4, const float* __restrict__ x,
    const float* __restrict__ xn,
    int* __restrict__ knn, float* __restrict__ ew, float* __restrict__ dis){
  int tid=threadIdx.x, bid=blockIdx.x;
  int gt=bid*256+tid;
  int lane=tid&63;
  int slot=gt>>5, part=tid&31;

  // --- KNN: numerics identical to r5-r9 ---
  float4 qv=sc4[slot]; int q=sidx[slot];
  float qx=qv.x,qy=qv.y,qz=qv.z,qs=qv.w;
  int cx=min(GC-1,(int)(qx*(float)GC)), cy=min(GC-1,(int)(qy*(float)GC)),
      cz=min(GC-1,(int)(qz*(float)GC));
  float D0=1e30f,D1=1e30f,D2=1e30f; int I0=0x7fffffff,I1=0x7fffffff,I2=0x7fffffff;
  int xlo=max(cx-1,0), xhi=min(cx+1,GC-1);
  for(int r=0;r<9;r++){
    int z2=cz+r/3-1, y2=cy+r%3-1;
    if(z2<0||z2>=GC||y2<0||y2>=GC) continue;
    int rowb=(z2*GC+y2)*GC;
    int p0=cellSt[rowb+xlo], p1=cellSt[rowb+xhi+1];  // x-cells contiguous
    for(int p=p0+part;p<p1;p+=32){
      float4 cv=sc4[p]; int j2=sidx[p];
      float dd=refdist(qx,qy,qz,qs,cv);
      dd=(j2==q)?1e30f:dd;
      lexins(dd,j2,D0,D1,D2,I0,I1,I2);
    }
  }
  #pragma unroll
  for(int m=1;m<32;m<<=1){
    float e0=__shfl_xor(D0,m),e1=__shfl_xor(D1,m),e2=__shfl_xor(D2,m);
    int   f0=__shfl_xor(I0,m),f1=__shfl_xor(I1,m),f2=__shfl_xor(I2,m);
    lexins(e0,f0,D0,D1,D2,I0,I1,I2);
    lexins(e1,f1,D0,D1,D2,I0,I1,I2);
    lexins(e2,f2,D0,D1,D2,I0,I1,I2);
  }
  bool flg=false;
  if(part==0){
    const float cw=1.0f/(float)GC;
    float mg=1e30f;
    mg=fminf(mg,(cx>0)?(qx-(float)(cx-1)*cw):1e30f);
    mg=fminf(mg,(cx<GC-1)?((float)(cx+2)*cw-qx):1e30f);
    mg=fminf(mg,(cy>0)?(qy-(float)(cy-1)*cw):1e30f);
    mg=fminf(mg,(cy<GC-1)?((float)(cy+2)*cw-qy):1e30f);
    mg=fminf(mg,(cz>0)?(qz-(float)(cz-1)*cw):1e30f);
    mg=fminf(mg,(cz<GC-1)?((float)(cz+2)*cw-qz):1e30f);
    float mg2=mg*mg*(1.0f-1e-5f);   // slack for dd rounding
    flg=!(D2<mg2);                  // at GC=8: ~never true
  }
  // safety-net fallback, expected ~0 queries
  unsigned long long mask=__ballot(flg);
  while(mask){
    int b=__ffsll((unsigned long long)mask)-1; mask&=mask-1;
    int qb=__shfl(q,b);
    float bx=__shfl(qx,b),by=__shfl(qy,b),bz=__shfl(qz,b),bs=__shfl(qs,b);
    float E0=1e30f,E1=1e30f,E2=1e30f; int F0=0x7fffffff,F1=0x7fffffff,F2=0x7fffffff;
    for(int j=lane;j<N;j+=64){
      float4 cv=c4[j];
      float dd=refdist(bx,by,bz,bs,cv);
      dd=(j==qb)?1e30f:dd;
      lexins(dd,j,E0,E1,E2,F0,F1,F2);
    }
    #pragma unroll
    for(int m=1;m<64;m<<=1){
      float e0=__shfl_xor(E0,m),e1=__shfl_xor(E1,m),e2=__shfl_xor(E2,m);
      int   f0=__shfl_xor(F0,m),f1=__shfl_xor(F1,m),f2=__shfl_xor(F2,m);
      lexins(e0,f0,E0,E1,E2,F0,F1,F2);
      lexins(e1,f1,E0,E1,E2,F0,F1,F2);
      lexins(e2,f2,E0,E1,E2,F0,F1,F2);
    }
    if(lane==b){ I0=F0; I1=F1; I2=F2; }
  }
  if(part==0){ knn[q*3+0]=I0; knn[q*3+1]=I1; knn[q*3+2]=I2; }

  // --- ew + dis for the wave's 2 queries (neighbor loads hoisted) ---
  for(int r=0;r<2;r++){
    int qi=__shfl(q,32*r);
    int s0=__shfl(I0,32*r), s1=__shfl(I1,32*r), s2=__shfl(I2,32*r);
    float xi=x[qi*64+lane];
    float xs0=x[s0*64+lane], xs1=x[s1*64+lane], xs2=x[s2*64+lane];
    float n0=xn[s0], n1=xn[s1], n2=xn[s2];
    float ni=xn[qi];
    float dt0=wsum(xs0*xi), dt1=wsum(xs1*xi), dt2=wsum(xs2*xi);
    float e0=1.f/(1.f+expf(-(dt0/(n0*ni))));
    float e1=1.f/(1.f+expf(-(dt1/(n1*ni))));
    float e2=1.f/(1.f+expf(-(dt2/(n2*ni))));
    if(lane==0){
      ew[qi*3+0]=e0; ew[qi*3+1]=e1; ew[qi*3+2]=e2;
      float ssum=((e0+e1)+e2);
      dis[qi]=1.f/sqrtf(ssum+1.0f);             // deg = 1 (self loop) + sum(ew)
    }
  }
}

// ---- K4: xa = weighted-agg(x); a1 = relu(LN(xa@W1 + b1)). Wave per 4 nodes. ----
// W column held in 64 VGPRs per lane (lane L owns W[:,L]) -> zero LDS reads
// for W; only 16 b128 broadcast reads of the xa row per node.
__global__ __launch_bounds__(256) void agg1_w1(const float* __restrict__ x,
    const float* __restrict__ ew, const float* __restrict__ dis,
    const int* __restrict__ knn, const float* __restrict__ W1,
    const float* __restrict__ bb1, const float* __restrict__ gg,
    const float* __restrict__ gb, float* __restrict__ a1){
  __shared__ float rowbuf[4][64];
  int tid=threadIdx.x;
  int wave=tid>>6, lane=tid&63;
  float wcol[64];
  #pragma unroll
  for(int k=0;k<64;k++) wcol[k]=W1[k*64+lane];   // coalesced, L2-hit
  float bv=bb1[lane], gv=gg[lane], bv2=gb[lane];
  int nb=blockIdx.x*16+wave*4;
  for(int r=0;r<4;r++){
    int i=nb+r;
    float di=dis[i];
    float xa=x[i*64+lane]*(di*di);            // self loop, ew=1
    #pragma unroll
    for(int m=0;m<3;m++){
      int s=knn[i*3+m];
      xa+=x[s*64+lane]*(dis[s]*ew[i*3+m]*di);
    }
    rowbuf[wave][lane]=xa;                    // wave-synchronous LDS bounce
    const float4* rb=(const float4*)&rowbuf[wave][0];
    float acc=0.f;
    #pragma unroll
    for(int k4=0;k4<16;k4++){
      float4 av=rb[k4];                       // broadcast read
      acc=fmaf(av.x,wcol[k4*4+0],acc);
      acc=fmaf(av.y,wcol[k4*4+1],acc);
      acc=fmaf(av.z,wcol[k4*4+2],acc);
      acc=fmaf(av.w,wcol[k4*4+3],acc);
    }
    acc+=bv;
    float mu=wsum(acc)*(1.0f/64.0f);
    float dd=acc-mu;
    float var=wsum(dd*dd)*(1.0f/64.0f);
    float y=dd*(1.0f/sqrtf(var+1e-5f))*gv+bv2;
    a1[i*64+lane]=fmaxf(y,0.0f);
  }
}

// ---- K5: aa = weighted-agg(a1); out = aa@W2 + b2 + 2x. Wave per 4 nodes. ----
__global__ __launch_bounds__(256) void agg2_w2(const float* __restrict__ a1,
    const float* __restrict__ ew, const float* __restrict__ dis,
    const int* __restrict__ knn, const float* __restrict__ W2,
    const float* __restrict__ bb2, const float* __restrict__ x,
    float* __restrict__ out){
  __shared__ float rowbuf[4][64];
  int tid=threadIdx.x;
  int wave=tid>>6, lane=tid&63;
  float wcol[64];
  #pragma unroll
  for(int k=0;k<64;k++) wcol[k]=W2[k*64+lane];   // coalesced, L2-hit
  float bv=bb2[lane];
  int nb=blockIdx.x*16+wave*4;
  for(int r=0;r<4;r++){
    int i=nb+r;
    float di=dis[i];
    float aa=a1[i*64+lane]*(di*di);
    #pragma unroll
    for(int m=0;m<3;m++){
      int s=knn[i*3+m];
      aa+=a1[s*64+lane]*(dis[s]*ew[i*3+m]*di);
    }
    rowbuf[wave][lane]=aa;
    const float4* rb=(const float4*)&rowbuf[wave][0];
    float acc=0.f;
    #pragma unroll
    for(int k4=0;k4<16;k4++){
      float4 av=rb[k4];
      acc=fmaf(av.x,wcol[k4*4+0],acc);
      acc=fmaf(av.y,wcol[k4*4+1],acc);
      acc=fmaf(av.z,wcol[k4*4+2],acc);
      acc=fmaf(av.w,wcol[k4*4+3],acc);
    }
    acc+=bv;
    float xv=x[i*64+lane];
    out[i*64+lane]=(acc+xv)+xv;  // (gcn2 + x) + shortcut, shortcut == x
  }
}

extern "C" void kernel_launch(void* const* d_in, const int* in_sizes, int n_in,
                              void* d_out, int out_size, void* d_ws, size_t ws_size,
                              hipStream_t stream){
  const float* feat  =(const float*)d_in[0];
  // d_in[1] edge_index_tran, d_in[2] edge_attr_rpe, d_in[3] norm_index: unused by reference
  const float* coords=(const float*)d_in[4];
  const float* g1 =(const float*)d_in[5];
  const float* b1n=(const float*)d_in[6];
  const float* g2 =(const float*)d_in[7];
  const float* b2n=(const float*)d_in[8];
  const float* gg =(const float*)d_in[9];
  const float* gb =(const float*)d_in[10];
  const float* W1 =(const float*)d_in[11];
  const float* bb1=(const float*)d_in[12];
  const float* W2 =(const float*)d_in[13];
  const float* bb2=(const float*)d_in[14];
  float* out=(float*)d_out;

  char* ws=(char*)d_ws;
  size_t o=0;
  float*  x      =(float*) (ws+o); o+=(size_t)N*64*4;    // post-LN2 features
  float*  a1     =(float*) (ws+o); o+=(size_t)N*64*4;    // activated GCN1 output
  float*  xn     =(float*) (ws+o); o+=(size_t)N*4;       // row norms of x
  float*  ew     =(float*) (ws+o); o+=(size_t)N*3*4;     // knn edge weights
  float*  dis    =(float*) (ws+o); o+=(size_t)N*4;       // 1/sqrt(deg)
  int*    knn    =(int*)   (ws+o); o+=(size_t)N*3*4;     // neighbor indices
  float4* c4     =(float4*)(ws+o); o+=(size_t)N*16;      // (x,y,z,sq) original order
  float4* sc4    =(float4*)(ws+o); o+=(size_t)N*16;      // cell-sorted
  int*    sidx   =(int*)   (ws+o); o+=(size_t)N*4;       // sorted -> original
  int*    cellSt =(int*)   (ws+o); o+=(size_t)(NCELL+1)*4;
  (void)ws_size; (void)in_sizes; (void)n_in; (void)out_size;

  hipLaunchKernelGGL(ln_kernel, dim3(N/4),  dim3(256),  0, stream, feat,g1,b1n,g2,b2n,coords,x,xn,c4);
  hipLaunchKernelGGL(prep,      dim3(1),    dim3(1024), 0, stream, c4,sc4,sidx,cellSt);
  hipLaunchKernelGGL(knn_ew,    dim3(2048), dim3(256),  0, stream, sc4,sidx,cellSt,c4,x,xn,knn,ew,dis);
  hipLaunchKernelGGL(agg1_w1,   dim3(N/16), dim3(256),  0, stream, x,ew,dis,knn,W1,bb1,gg,gb,a1);
  hipLaunchKernelGGL(agg2_w2,   dim3(N/16), dim3(256),  0, stream, a1,ew,dis,knn,W2,bb2,x,out);
}

// Round 11
// 166.980 us; speedup vs baseline: 3.2774x; 1.0011x over previous
//
#include <hip/hip_runtime.h>
#include <math.h>

#define N 16384
#define GC 8             // grid cells per dim (margin >= 1/8 -> fallback ~never fires)
#define NCELL (GC*GC*GC) // 512

__device__ __forceinline__ float wsum(float v){
  #pragma unroll
  for(int m=32;m>0;m>>=1) v += __shfl_xor(v,m,64);
  return v;
}

// branchless lexicographic (d,idx) top-3 insert; matches jax top_k stable tie-break
__device__ __forceinline__ void lexins(float dd,int j2,
    float&D0,float&D1,float&D2,int&I0,int&I1,int&I2){
  bool lt0=(dd<D0)||((dd==D0)&&(j2<I0));
  bool lt1=(dd<D1)||((dd==D1)&&(j2<I1));
  bool lt2=(dd<D2)||((dd==D2)&&(j2<I2));
  float nD2=lt1?D1:(lt2?dd:D2); int nI2=lt1?I1:(lt2?j2:I2);
  float nD1=lt0?D0:(lt1?dd:D1); int nI1=lt0?I0:(lt1?j2:I1);
  float nD0=lt0?dd:D0;          int nI0=lt0?j2:I0;
  D0=nD0;D1=nD1;D2=nD2;I0=nI0;I1=nI1;I2=nI2;
}

// reference-exact squared distance: dd = rn(rn(qs+cs) - 2*dot), dot FMA chain
__device__ __forceinline__ float refdist(float qx,float qy,float qz,float qs,float4 cv){
  float dot=__fmaf_rn(qz,cv.z,__fmaf_rn(qy,cv.y,__fmul_rn(qx,cv.x)));
  float sc =__fadd_rn(qs,cv.w);
  return __fmaf_rn(-2.0f,dot,sc);
}

// ---- K1: LN -> x2 -> LN, row L2 norms, c4=(x,y,z,sq). One wave per row. ----
__global__ __launch_bounds__(256) void ln_kernel(const float* __restrict__ in,
    const float* __restrict__ g1,const float* __restrict__ b1,
    const float* __restrict__ g2,const float* __restrict__ b2,
    const float* __restrict__ coords,
    float* __restrict__ x, float* __restrict__ xn, float4* __restrict__ c4){
  int wave=threadIdx.x>>6, lane=threadIdx.x&63;
  int row=blockIdx.x*4+wave;
  float v=in[row*64+lane];
  float m=wsum(v)*(1.0f/64.0f);
  float d=v-m;
  float var=wsum(d*d)*(1.0f/64.0f);
  float y=d*(1.0f/sqrtf(var+1e-5f))*g1[lane]+b1[lane];
  y=y+y;  // transformer stubbed as identity + shortcut
  float m2=wsum(y)*(1.0f/64.0f);
  float d2=y-m2;
  float var2=wsum(d2*d2)*(1.0f/64.0f);
  float z=d2*(1.0f/sqrtf(var2+1e-5f))*g2[lane]+b2[lane];
  x[row*64+lane]=z;
  float s=wsum(z*z);
  if(lane==0){
    xn[row]=fmaxf(sqrtf(s),1e-8f);
    float a=coords[row*3+0],b=coords[row*3+1],c=coords[row*3+2];
    float sq=__fadd_rn(__fadd_rn(__fmul_rn(a,a),__fmul_rn(b,b)),__fmul_rn(c,c));
    c4[row]=make_float4(a,b,c,sq);
  }
}

// ---- K2: single-block prep (1024 threads): LDS histogram + scan + scatter. ----
__global__ __launch_bounds__(1024) void prep(const float4* __restrict__ c4,
    float4* __restrict__ sc4, int* __restrict__ sidx, int* __restrict__ cellSt){
  __shared__ int cnt[NCELL];
  __shared__ int scanbuf[NCELL];
  int tid=threadIdx.x;
  if(tid<NCELL) cnt[tid]=0;
  __syncthreads();
  for(int i=tid;i<N;i+=1024){
    float4 v=c4[i];
    int cx=min(GC-1,(int)(v.x*(float)GC)), cy=min(GC-1,(int)(v.y*(float)GC)),
        cz=min(GC-1,(int)(v.z*(float)GC));
    atomicAdd(&cnt[(cz*GC+cy)*GC+cx],1);
  }
  __syncthreads();
  if(tid<NCELL) scanbuf[tid]=cnt[tid];
  __syncthreads();
  for(int off=1;off<NCELL;off<<=1){
    int t=0;
    if(tid>=off && tid<NCELL) t=scanbuf[tid-off];
    __syncthreads();
    if(tid<NCELL) scanbuf[tid]+=t;
    __syncthreads();
  }
  if(tid<NCELL){
    int excl=scanbuf[tid]-cnt[tid];
    cellSt[tid]=excl; cnt[tid]=excl;
    if(tid==NCELL-1) cellSt[NCELL]=scanbuf[NCELL-1];
  }
  __syncthreads();
  for(int i=tid;i<N;i+=1024){
    float4 v=c4[i];
    int cx=min(GC-1,(int)(v.x*(float)GC)), cy=min(GC-1,(int)(v.y*(float)GC)),
        cz=min(GC-1,(int)(v.z*(float)GC));
    int pos=atomicAdd(&cnt[(cz*GC+cy)*GC+cx],1);
    sc4[pos]=v; sidx[pos]=i;
  }
}

// ---- K3: grid KNN (32 lanes/query, pruned cell runs) + edge weights. ----
// 2048 blocks x 256. Runs ordered center -> faces -> diagonals; a run is
// skipped iff its geometric lower bound dy^2+dz^2 exceeds current D2 plus
// conservative slack (1e-5 >> dd rounding error ~7e-7). Skip test is
// per-query-uniform; the whole-region margin check + fallback still
// certifies exactness, so pruning cannot change results.
__global__ __launch_bounds__(256) void knn_ew(const float4* __restrict__ sc4,
    const int* __restrict__ sidx, const int* __restrict__ cellSt,
    const float4* __restrict__ c4, const float* __restrict__ x,
    const float* __restrict__ xn,
    int* __restrict__ knn, float* __restrict__ ew, float* __restrict__ dis){
  int tid=threadIdx.x, bid=blockIdx.x;
  int gt=bid*256+tid;
  int lane=tid&63;
  int slot=gt>>5, part=tid&31;

  float4 qv=sc4[slot]; int q=sidx[slot];
  float qx=qv.x,qy=qv.y,qz=qv.z,qs=qv.w;
  int cx=min(GC-1,(int)(qx*(float)GC)), cy=min(GC-1,(int)(qy*(float)GC)),
      cz=min(GC-1,(int)(qz*(float)GC));
  float D0=1e30f,D1=1e30f,D2=1e30f; int I0=0x7fffffff,I1=0x7fffffff,I2=0x7fffffff;
  int xlo=max(cx-1,0), xhi=min(cx+1,GC-1);
  const float cw=1.0f/(float)GC;
  float fy0=qy-(float)cy*cw, fy1=(float)(cy+1)*cw-qy;   // dist to y faces
  float fz0=qz-(float)cz*cw, fz1=(float)(cz+1)*cw-qz;   // dist to z faces
  // run order: center, 4 faces, 4 diagonals  (oy, oz)
  const int OY[9]={0,-1,1, 0,0,-1, 1,-1,1};
  const int OZ[9]={0, 0,0,-1,1,-1,-1, 1,1};
  #pragma unroll 1
  for(int k=0;k<9;k++){
    int oy=OY[k], oz=OZ[k];
    int y2=cy+oy, z2=cz+oz;
    if(y2<0||y2>=GC||z2<0||z2>=GC) continue;
    if(k>0){
      float dy=(oy<0)?fy0:((oy>0)?fy1:0.0f);
      float dz=(oz<0)?fz0:((oz>0)?fz1:0.0f);
      float bnd=dy*dy+dz*dz;
      if(bnd>D2+1e-5f) continue;          // conservative skip
    }
    int rowb=(z2*GC+y2)*GC;
    int p0=cellSt[rowb+xlo], p1=cellSt[rowb+xhi+1];  // x-cells contiguous
    for(int p=p0+part;p<p1;p+=32){
      float4 cv=sc4[p]; int j2=sidx[p];
      float dd=refdist(qx,qy,qz,qs,cv);
      dd=(j2==q)?1e30f:dd;
      lexins(dd,j2,D0,D1,D2,I0,I1,I2);
    }
  }
  #pragma unroll
  for(int m=1;m<32;m<<=1){
    float e0=__shfl_xor(D0,m),e1=__shfl_xor(D1,m),e2=__shfl_xor(D2,m);
    int   f0=__shfl_xor(I0,m),f1=__shfl_xor(I1,m),f2=__shfl_xor(I2,m);
    lexins(e0,f0,D0,D1,D2,I0,I1,I2);
    lexins(e1,f1,D0,D1,D2,I0,I1,I2);
    lexins(e2,f2,D0,D1,D2,I0,I1,I2);
  }
  bool flg=false;
  if(part==0){
    float mg=1e30f;
    mg=fminf(mg,(cx>0)?(qx-(float)(cx-1)*cw):1e30f);
    mg=fminf(mg,(cx<GC-1)?((float)(cx+2)*cw-qx):1e30f);
    mg=fminf(mg,(cy>0)?(qy-(float)(cy-1)*cw):1e30f);
    mg=fminf(mg,(cy<GC-1)?((float)(cy+2)*cw-qy):1e30f);
    mg=fminf(mg,(cz>0)?(qz-(float)(cz-1)*cw):1e30f);
    mg=fminf(mg,(cz<GC-1)?((float)(cz+2)*cw-qz):1e30f);
    float mg2=mg*mg*(1.0f-1e-5f);   // slack for dd rounding
    flg=!(D2<mg2);                  // at GC=8: ~never true
  }
  // safety-net fallback, expected ~0 queries
  unsigned long long mask=__ballot(flg);
  while(mask){
    int b=__ffsll((unsigned long long)mask)-1; mask&=mask-1;
    int qb=__shfl(q,b);
    float bx=__shfl(qx,b),by=__shfl(qy,b),bz=__shfl(qz,b),bs=__shfl(qs,b);
    float E0=1e30f,E1=1e30f,E2=1e30f; int F0=0x7fffffff,F1=0x7fffffff,F2=0x7fffffff;
    for(int j=lane;j<N;j+=64){
      float4 cv=c4[j];
      float dd=refdist(bx,by,bz,bs,cv);
      dd=(j==qb)?1e30f:dd;
      lexins(dd,j,E0,E1,E2,F0,F1,F2);
    }
    #pragma unroll
    for(int m=1;m<64;m<<=1){
      float e0=__shfl_xor(E0,m),e1=__shfl_xor(E1,m),e2=__shfl_xor(E2,m);
      int   f0=__shfl_xor(F0,m),f1=__shfl_xor(F1,m),f2=__shfl_xor(F2,m);
      lexins(e0,f0,E0,E1,E2,F0,F1,F2);
      lexins(e1,f1,E0,E1,E2,F0,F1,F2);
      lexins(e2,f2,E0,E1,E2,F0,F1,F2);
    }
    if(lane==b){ I0=F0; I1=F1; I2=F2; }
  }
  if(part==0){ knn[q*3+0]=I0; knn[q*3+1]=I1; knn[q*3+2]=I2; }

  // --- ew + dis for the wave's 2 queries (neighbor loads hoisted) ---
  for(int r=0;r<2;r++){
    int qi=__shfl(q,32*r);
    int s0=__shfl(I0,32*r), s1=__shfl(I1,32*r), s2=__shfl(I2,32*r);
    float xi=x[qi*64+lane];
    float xs0=x[s0*64+lane], xs1=x[s1*64+lane], xs2=x[s2*64+lane];
    float n0=xn[s0], n1=xn[s1], n2=xn[s2];
    float ni=xn[qi];
    float dt0=wsum(xs0*xi), dt1=wsum(xs1*xi), dt2=wsum(xs2*xi);
    float e0=1.f/(1.f+expf(-(dt0/(n0*ni))));
    float e1=1.f/(1.f+expf(-(dt1/(n1*ni))));
    float e2=1.f/(1.f+expf(-(dt2/(n2*ni))));
    if(lane==0){
      ew[qi*3+0]=e0; ew[qi*3+1]=e1; ew[qi*3+2]=e2;
      float ssum=((e0+e1)+e2);
      dis[qi]=1.f/sqrtf(ssum+1.0f);             // deg = 1 (self loop) + sum(ew)
    }
  }
}

// ---- K4: xa = weighted-agg(x); a1 = relu(LN(xa@W1 + b1)). Wave per 4 nodes. ----
// W column held in 64 VGPRs per lane (lane L owns W[:,L]) -> zero LDS reads
// for W; only 16 b128 broadcast reads of the xa row per node.
__global__ __launch_bounds__(256) void agg1_w1(const float* __restrict__ x,
    const float* __restrict__ ew, const float* __restrict__ dis,
    const int* __restrict__ knn, const float* __restrict__ W1,
    const float* __restrict__ bb1, const float* __restrict__ gg,
    const float* __restrict__ gb, float* __restrict__ a1){
  __shared__ float rowbuf[4][64];
  int tid=threadIdx.x;
  int wave=tid>>6, lane=tid&63;
  float wcol[64];
  #pragma unroll
  for(int k=0;k<64;k++) wcol[k]=W1[k*64+lane];   // coalesced, L2-hit
  float bv=bb1[lane], gv=gg[lane], bv2=gb[lane];
  int nb=blockIdx.x*16+wave*4;
  for(int r=0;r<4;r++){
    int i=nb+r;
    float di=dis[i];
    float xa=x[i*64+lane]*(di*di);            // self loop, ew=1
    #pragma unroll
    for(int m=0;m<3;m++){
      int s=knn[i*3+m];
      xa+=x[s*64+lane]*(dis[s]*ew[i*3+m]*di);
    }
    rowbuf[wave][lane]=xa;                    // wave-synchronous LDS bounce
    const float4* rb=(const float4*)&rowbuf[wave][0];
    float acc=0.f;
    #pragma unroll
    for(int k4=0;k4<16;k4++){
      float4 av=rb[k4];                       // broadcast read
      acc=fmaf(av.x,wcol[k4*4+0],acc);
      acc=fmaf(av.y,wcol[k4*4+1],acc);
      acc=fmaf(av.z,wcol[k4*4+2],acc);
      acc=fmaf(av.w,wcol[k4*4+3],acc);
    }
    acc+=bv;
    float mu=wsum(acc)*(1.0f/64.0f);
    float dd=acc-mu;
    float var=wsum(dd*dd)*(1.0f/64.0f);
    float y=dd*(1.0f/sqrtf(var+1e-5f))*gv+bv2;
    a1[i*64+lane]=fmaxf(y,0.0f);
  }
}

// ---- K5: aa = weighted-agg(a1); out = aa@W2 + b2 + 2x. Wave per 4 nodes. ----
__global__ __launch_bounds__(256) void agg2_w2(const float* __restrict__ a1,
    const float* __restrict__ ew, const float* __restrict__ dis,
    const int* __restrict__ knn, const float* __restrict__ W2,
    const float* __restrict__ bb2, const float* __restrict__ x,
    float* __restrict__ out){
  __shared__ float rowbuf[4][64];
  int tid=threadIdx.x;
  int wave=tid>>6, lane=tid&63;
  float wcol[64];
  #pragma unroll
  for(int k=0;k<64;k++) wcol[k]=W2[k*64+lane];   // coalesced, L2-hit
  float bv=bb2[lane];
  int nb=blockIdx.x*16+wave*4;
  for(int r=0;r<4;r++){
    int i=nb+r;
    float di=dis[i];
    float aa=a1[i*64+lane]*(di*di);
    #pragma unroll
    for(int m=0;m<3;m++){
      int s=knn[i*3+m];
      aa+=a1[s*64+lane]*(dis[s]*ew[i*3+m]*di);
    }
    rowbuf[wave][lane]=aa;
    const float4* rb=(const float4*)&rowbuf[wave][0];
    float acc=0.f;
    #pragma unroll
    for(int k4=0;k4<16;k4++){
      float4 av=rb[k4];
      acc=fmaf(av.x,wcol[k4*4+0],acc);
      acc=fmaf(av.y,wcol[k4*4+1],acc);
      acc=fmaf(av.z,wcol[k4*4+2],acc);
      acc=fmaf(av.w,wcol[k4*4+3],acc);
    }
    acc+=bv;
    float xv=x[i*64+lane];
    out[i*64+lane]=(acc+xv)+xv;  // (gcn2 + x) + shortcut, shortcut == x
  }
}

extern "C" void kernel_launch(void* const* d_in, const int* in_sizes, int n_in,
                              void* d_out, int out_size, void* d_ws, size_t ws_size,
                              hipStream_t stream){
  const float* feat  =(const float*)d_in[0];
  // d_in[1] edge_index_tran, d_in[2] edge_attr_rpe, d_in[3] norm_index: unused by reference
  const float* coords=(const float*)d_in[4];
  const float* g1 =(const float*)d_in[5];
  const float* b1n=(const float*)d_in[6];
  const float* g2 =(const float*)d_in[7];
  const float* b2n=(const float*)d_in[8];
  const float* gg =(const float*)d_in[9];
  const float* gb =(const float*)d_in[10];
  const float* W1 =(const float*)d_in[11];
  const float* bb1=(const float*)d_in[12];
  const float* W2 =(const float*)d_in[13];
  const float* bb2=(const float*)d_in[14];
  float* out=(float*)d_out;

  char* ws=(char*)d_ws;
  size_t o=0;
  float*  x      =(float*) (ws+o); o+=(size_t)N*64*4;    // post-LN2 features
  float*  a1     =(float*) (ws+o); o+=(size_t)N*64*4;    // activated GCN1 output
  float*  xn     =(float*) (ws+o); o+=(size_t)N*4;       // row norms of x
  float*  ew     =(float*) (ws+o); o+=(size_t)N*3*4;     // knn edge weights
  float*  dis    =(float*) (ws+o); o+=(size_t)N*4;       // 1/sqrt(deg)
  int*    knn    =(int*)   (ws+o); o+=(size_t)N*3*4;     // neighbor indices
  float4* c4     =(float4*)(ws+o); o+=(size_t)N*16;      // (x,y,z,sq) original order
  float4* sc4    =(float4*)(ws+o); o+=(size_t)N*16;      // cell-sorted
  int*    sidx   =(int*)   (ws+o); o+=(size_t)N*4;       // sorted -> original
  int*    cellSt =(int*)   (ws+o); o+=(size_t)(NCELL+1)*4;
  (void)ws_size; (void)in_sizes; (void)n_in; (void)out_size;

  hipLaunchKernelGGL(ln_kernel, dim3(N/4),  dim3(256),  0, stream, feat,g1,b1n,g2,b2n,coords,x,xn,c4);
  hipLaunchKernelGGL(prep,      dim3(1),    dim3(1024), 0, stream, c4,sc4,sidx,cellSt);
  hipLaunchKernelGGL(knn_ew,    dim3(2048), dim3(256),  0, stream, sc4,sidx,cellSt,c4,x,xn,knn,ew,dis);
  hipLaunchKernelGGL(agg1_w1,   dim3(N/16), dim3(256),  0, stream, x,ew,dis,knn,W1,bb1,gg,gb,a1);
  hipLaunchKernelGGL(agg2_w2,   dim3(N/16), dim3(256),  0, stream, a1,ew,dis,knn,W2,bb2,x,out);
}